// Round 7
// baseline (1936.591 us; speedup 1.0000x reference)
//
#include <hip/hip_runtime.h>

typedef unsigned short u16;
typedef unsigned int u32;
typedef __bf16 bf16x8 __attribute__((ext_vector_type(8)));
typedef float f32x4 __attribute__((ext_vector_type(4)));
typedef float f32x2 __attribute__((ext_vector_type(2)));

#define AS_STRIDE 136   // bf16 elems per LDS A-row (128 + 8 pad; 16B-aligned rows)

__device__ __forceinline__ u16 f2bf1(float f) {
  union { __bf16 h; u16 u; } c; c.h = (__bf16)f; return c.u;
}
__device__ __forceinline__ u32 cvt2bf(float a, float b) {
  union { __bf16 h[2]; u32 u; } c; c.h[0] = (__bf16)a; c.h[1] = (__bf16)b; return c.u;
}
__device__ __forceinline__ float bf2f(u16 u) {
  union { u32 u; float f; } v; v.u = ((u32)u) << 16; return v.f;
}
// silu via v_rcp_f32 (2 ops) instead of IEEE f32 divide (~10-op sequence)
__device__ __forceinline__ float silu_f(float a) {
  return a * __builtin_amdgcn_rcpf(1.f + __expf(-a));
}
__device__ __forceinline__ float rsq_f(float x) {
  return __builtin_amdgcn_rsqf(x);
}
__device__ __forceinline__ f32x2 unpk2(u32 p) {
  union { u32 u; float f; } a, b;
  a.u = p << 16; b.u = p & 0xffff0000u;
  return (f32x2){a.f, b.f};
}

// ---------------- edge sort by dst (counting sort, once per call) ------------
__global__ void edge_hist(const int* __restrict__ edst, int E, int* __restrict__ cnt) {
  int i = blockIdx.x * blockDim.x + threadIdx.x;
  if (i < E) atomicAdd(&cnt[edst[i]], 1);
}

__global__ __launch_bounds__(1024)
void scan_kernel(const int* __restrict__ cnt, int* __restrict__ cursor, int Nn) {
  __shared__ int part[1024];
  int t = threadIdx.x;
  int per = (Nn + 1023) / 1024;
  int b = t * per;
  int s = 0;
  for (int i = 0; i < per; i++) { int idx = b + i; if (idx < Nn) s += cnt[idx]; }
  part[t] = s;
  __syncthreads();
  for (int d = 1; d < 1024; d <<= 1) {
    int v = (t >= d) ? part[t - d] : 0;
    __syncthreads();
    part[t] += v;
    __syncthreads();
  }
  int excl = (t == 0) ? 0 : part[t - 1];
  for (int i = 0; i < per; i++) {
    int idx = b + i;
    if (idx < Nn) { cursor[idx] = excl; excl += cnt[idx]; }
  }
}

__global__ void edge_scatter(const int* __restrict__ esrc, const int* __restrict__ edst,
                             int E, int* __restrict__ cursor,
                             int* __restrict__ ssrc, int* __restrict__ sdst) {
  int i = blockIdx.x * blockDim.x + threadIdx.x;
  if (i < E) {
    int d = edst[i];
    int p = atomicAdd(&cursor[d], 1);
    ssrc[p] = esrc[i];
    sdst[p] = d;
  }
}

// ---------------- weight prep: transpose + bf16-cast -------------------------
__global__ void prep_weights(const float* __restrict__ e_w1, const float* __restrict__ e_w2,
                             const float* __restrict__ n_w1, const float* __restrict__ n_w2,
                             u16* __restrict__ eW1T, u16* __restrict__ eW2T,
                             u16* __restrict__ nW1T, u16* __restrict__ nW2T) {
  int i = blockIdx.x * blockDim.x + threadIdx.x;
  const int s1 = 3 * 128 * 256;
  const int s2 = 3 * 128 * 128;
  if (i < s1) {
    int l = i / 32768, r = i % 32768, n = r >> 8, k = r & 255;
    eW1T[i] = f2bf1(e_w1[l * 33408 + k * 128 + n]);
  } else if (i < s1 + s2) {
    int j = i - s1; int l = j / 16384, r = j % 16384, n = r >> 7, k = r & 127;
    eW2T[j] = f2bf1(e_w2[l * 16384 + k * 128 + n]);
  } else if (i < s1 + s2 + s1) {
    int j = i - s1 - s2; int l = j / 32768, r = j % 32768, n = r >> 8, k = r & 255;
    nW1T[j] = f2bf1(n_w1[l * 32768 + k * 128 + n]);
  } else if (i < 2 * s1 + 2 * s2) {
    int j = i - 2 * s1 - s2; int l = j / 16384, r = j % 16384, n = r >> 7, k = r & 127;
    nW2T[j] = f2bf1(n_w2[l * 16384 + k * 128 + n]);
  }
}

// enc/dec weights (edge-attr weight consumed as f32 directly from e_w1)
__global__ void prep_weights2(const float* __restrict__ enc_w1, const float* __restrict__ enc_w2,
                              const float* __restrict__ dec_w1, const float* __restrict__ dec_w2,
                              const float* __restrict__ dec_w3,
                              u16* __restrict__ encW1T, u16* __restrict__ encW2T,
                              u16* __restrict__ decW1T, u16* __restrict__ decW2T,
                              u16* __restrict__ decW3T) {
  int i = blockIdx.x * blockDim.x + threadIdx.x;
  if (i < 4096) {
    int n = i >> 5, k = i & 31;
    encW1T[i] = (k < 7) ? f2bf1(enc_w1[k * 128 + n]) : (u16)0;
  } else if (i < 20480) {
    int j = i - 4096; int n = j >> 7, k = j & 127;
    encW2T[j] = f2bf1(enc_w2[k * 128 + n]);
  } else if (i < 36864) {
    int j = i - 20480; int n = j >> 7, k = j & 127;
    decW1T[j] = f2bf1(dec_w1[k * 128 + n]);
  } else if (i < 45056) {
    int j = i - 36864; int n = j >> 7, k = j & 127;
    decW2T[j] = f2bf1(dec_w2[k * 64 + n]);
  } else if (i < 46080) {
    int j = i - 45056; int n = j >> 6, k = j & 63;
    decW3T[j] = (n < 6) ? f2bf1(dec_w3[k * 6 + n]) : (u16)0;
  }
}

// ---------------- encoder (MFMA) + fused hd/hs for layer 0 -------------------
__global__ __launch_bounds__(256, 4)
void encoder_mfma(const float* __restrict__ x,
                  const u16* __restrict__ W1T,   // [128][32]
                  const float* __restrict__ b1,
                  const float* __restrict__ g, const float* __restrict__ be,
                  const u16* __restrict__ W2T,   // [128][128]
                  const float* __restrict__ b2,
                  const u16* __restrict__ eW1T0, // [128][256] layer-0 edge W1
                  const float* __restrict__ eb10,
                  u16* __restrict__ hbf, u16* __restrict__ hd_all,
                  u16* __restrict__ hs_all, int Nn) {
  __shared__ __align__(16) u16 As[64 * 40];
  __shared__ __align__(16) u16 ts[64 * AS_STRIDE];
  const int tid = threadIdx.x;
  const int m0 = blockIdx.x * 64;
  const int w = tid >> 6, lane = tid & 63, quad = lane >> 4, l16 = lane & 15;
  const int c0w = w * 32;

  if (tid < 64) {
    int node = m0 + tid; if (node >= Nn) node = Nn - 1;
    union { u16 us[32]; uint4 v[4]; } pk;
    #pragma unroll
    for (int k = 0; k < 32; k++) pk.us[k] = 0;
    #pragma unroll
    for (int k = 0; k < 7; k++) pk.us[k] = f2bf1(x[node * 7 + k]);
    #pragma unroll
    for (int k = 0; k < 4; k++) *(uint4*)(As + tid * 40 + k * 8) = pk.v[k];
  }
  __syncthreads();

  f32x4 acc[4][2];
  #pragma unroll
  for (int rt = 0; rt < 4; rt++)
    #pragma unroll
    for (int ct = 0; ct < 2; ct++)
      acc[rt][ct] = (f32x4){0.f, 0.f, 0.f, 0.f};
  {
    const int kl = quad * 8;
    bf16x8 af[4];
    #pragma unroll
    for (int rt = 0; rt < 4; rt++)
      af[rt] = *(const bf16x8*)(As + (rt * 16 + l16) * 40 + kl);
    #pragma unroll
    for (int ct = 0; ct < 2; ct++) {
      bf16x8 bfv = *(const bf16x8*)(W1T + (c0w + ct * 16 + l16) * 32 + kl);
      #pragma unroll
      for (int rt = 0; rt < 4; rt++)
        acc[rt][ct] = __builtin_amdgcn_mfma_f32_16x16x32_bf16(af[rt], bfv, acc[rt][ct], 0, 0, 0);
    }
  }
  #pragma unroll
  for (int ct = 0; ct < 2; ct++) {
    int n = c0w + ct * 16 + l16;
    float b1v = b1[n];
    #pragma unroll
    for (int rt = 0; rt < 4; rt++)
      #pragma unroll
      for (int r = 0; r < 4; r++)
        ts[(rt * 16 + quad * 4 + r) * AS_STRIDE + n] = f2bf1(acc[rt][ct][r] + b1v);
  }
  __syncthreads();

  { // LN + SiLU in place (bf16)
    int row = tid >> 2, sub = tid & 3;
    float s = 0.f, sq = 0.f, vals[32];
    #pragma unroll
    for (int i = 0; i < 32; i++) {
      float v = bf2f(ts[row * AS_STRIDE + sub + i * 4]);
      vals[i] = v; s += v; sq += v * v;
    }
    s += __shfl_xor(s, 1); sq += __shfl_xor(sq, 1);
    s += __shfl_xor(s, 2); sq += __shfl_xor(sq, 2);
    float mean = s * (1.f / 128.f);
    float rstd = rsq_f(sq * (1.f / 128.f) - mean * mean + 1e-5f);
    #pragma unroll
    for (int i = 0; i < 32; i++) {
      int c = sub + i * 4;
      float a = (vals[i] - mean) * rstd * g[c] + be[c];
      ts[row * AS_STRIDE + c] = f2bf1(silu_f(a));
    }
  }
  __syncthreads();

  f32x4 acc2[4][2];
  #pragma unroll
  for (int rt = 0; rt < 4; rt++)
    #pragma unroll
    for (int ct = 0; ct < 2; ct++)
      acc2[rt][ct] = (f32x4){0.f, 0.f, 0.f, 0.f};
  #pragma unroll
  for (int kk = 0; kk < 4; kk++) {
    const int kl = kk * 32 + quad * 8;
    bf16x8 af[4];
    #pragma unroll
    for (int rt = 0; rt < 4; rt++)
      af[rt] = *(const bf16x8*)(ts + (rt * 16 + l16) * AS_STRIDE + kl);
    #pragma unroll
    for (int ct = 0; ct < 2; ct++) {
      bf16x8 bfv = *(const bf16x8*)(W2T + (size_t)(c0w + ct * 16 + l16) * 128 + kl);
      #pragma unroll
      for (int rt = 0; rt < 4; rt++)
        acc2[rt][ct] = __builtin_amdgcn_mfma_f32_16x16x32_bf16(af[rt], bfv, acc2[rt][ct], 0, 0, 0);
    }
  }
  __syncthreads();   // ts reads done; rewrite with h
  #pragma unroll
  for (int ct = 0; ct < 2; ct++) {
    int n = c0w + ct * 16 + l16;
    float b2v = b2[n];
    #pragma unroll
    for (int rt = 0; rt < 4; rt++)
      #pragma unroll
      for (int r = 0; r < 4; r++) {
        int m = rt * 16 + quad * 4 + r;
        int node = m0 + m;
        u16 hb = f2bf1(acc2[rt][ct][r] + b2v);
        ts[m * AS_STRIDE + n] = hb;
        if (node < Nn) hbf[(size_t)node * 128 + n] = hb;
      }
  }
  __syncthreads();

  { // fused hd = h@W1d + b1, then hs = h@W1s (layer 0)
    f32x4 ah[4][2];
    #pragma unroll
    for (int rt = 0; rt < 4; rt++)
      #pragma unroll
      for (int ct = 0; ct < 2; ct++)
        ah[rt][ct] = (f32x4){0.f, 0.f, 0.f, 0.f};
    #pragma unroll
    for (int kk = 0; kk < 4; kk++) {
      const int kl = kk * 32 + quad * 8;
      bf16x8 af[4];
      #pragma unroll
      for (int rt = 0; rt < 4; rt++)
        af[rt] = *(const bf16x8*)(ts + (rt * 16 + l16) * AS_STRIDE + kl);
      #pragma unroll
      for (int ct = 0; ct < 2; ct++) {
        bf16x8 bd = *(const bf16x8*)(eW1T0 + (size_t)(c0w + ct * 16 + l16) * 256 + kl);
        #pragma unroll
        for (int rt = 0; rt < 4; rt++)
          ah[rt][ct] = __builtin_amdgcn_mfma_f32_16x16x32_bf16(af[rt], bd, ah[rt][ct], 0, 0, 0);
      }
    }
    #pragma unroll
    for (int ct = 0; ct < 2; ct++) {
      int n = c0w + ct * 16 + l16;
      float b1v = eb10[n];
      #pragma unroll
      for (int rt = 0; rt < 4; rt++)
        #pragma unroll
        for (int r = 0; r < 4; r++) {
          int node = m0 + rt * 16 + quad * 4 + r;
          if (node < Nn) hd_all[(size_t)node * 128 + n] = f2bf1(ah[rt][ct][r] + b1v);
        }
    }
    #pragma unroll
    for (int rt = 0; rt < 4; rt++)
      #pragma unroll
      for (int ct = 0; ct < 2; ct++)
        ah[rt][ct] = (f32x4){0.f, 0.f, 0.f, 0.f};
    #pragma unroll
    for (int kk = 0; kk < 4; kk++) {
      const int kl = kk * 32 + quad * 8;
      bf16x8 af[4];
      #pragma unroll
      for (int rt = 0; rt < 4; rt++)
        af[rt] = *(const bf16x8*)(ts + (rt * 16 + l16) * AS_STRIDE + kl);
      #pragma unroll
      for (int ct = 0; ct < 2; ct++) {
        bf16x8 bs = *(const bf16x8*)(eW1T0 + (size_t)(c0w + ct * 16 + l16) * 256 + 128 + kl);
        #pragma unroll
        for (int rt = 0; rt < 4; rt++)
          ah[rt][ct] = __builtin_amdgcn_mfma_f32_16x16x32_bf16(af[rt], bs, ah[rt][ct], 0, 0, 0);
      }
    }
    #pragma unroll
    for (int ct = 0; ct < 2; ct++) {
      int n = c0w + ct * 16 + l16;
      #pragma unroll
      for (int rt = 0; rt < 4; rt++)
        #pragma unroll
        for (int r = 0; r < 4; r++) {
          int node = m0 + rt * 16 + quad * 4 + r;
          if (node < Nn) hs_all[(size_t)node * 128 + n] = f2bf1(ah[rt][ct][r]);
        }
    }
  }
}

// ---------------- edge MLP: fully wave-independent 16-edge tiles (r10) -------
// r10: each wave owns 16 edges end-to-end: own gather -> phase A -> private
// 16x136 LDS tile -> own 16x128 W2 MFMA (A-frag row l16, 8 ct x 4 kk) ->
// col-major msg pack (aliases tile) -> per-wave 16-edge flush. ZERO barriers;
// all LDS sharing is intra-wave (compiler-ordered lgkmcnt). Atomic count
// unchanged vs r9 (16-edge windows per column). b2 moved to node via cnt.
// LDS padded to 23552B to pin 6 blocks/CU (7 would risk r3-style L2 thrash).
__global__ __launch_bounds__(256, 6)
void edge_mlp_kernel(const int* __restrict__ ssrc, const int* __restrict__ sdst,
                     const float* __restrict__ pos,
                     const u16* __restrict__ hd_all, const u16* __restrict__ hs_all,
                     const float* __restrict__ w1cF, // [5][128] f32 (= e_w1 rows 256..260)
                     const float* __restrict__ g, const float* __restrict__ be,
                     const u16* __restrict__ W2T,   // [128][128] bf16
                     float* __restrict__ aggr) {
  __shared__ int s_dstw[4][16];
  __shared__ __align__(16) float s_eaw[4][16 * 9];   // stride 9: quads hit distinct banks
  __shared__ __align__(16) u16 s_slab[4][2624];      // tile [16][136] aliased by msg [128][20]

  const int tid = threadIdx.x;
  // XCD swizzle: consecutive-dst chunks stay on one XCD
  const int bid = blockIdx.x;
  const int eblk = (bid & 7) * (gridDim.x >> 3) + (bid >> 3);
  const int w = tid >> 6, lane = tid & 63, quad = lane >> 4, l16 = lane & 15;
  const int e0w = eblk * 64 + w * 16;
  const int c0 = l16 * 8;
  u16* tile = s_slab[w];
  u16* msg  = s_slab[w];
  float* s_ea = s_eaw[w];

  // ---- prefetch this wave's gathers at kernel top; fence pins issue order ----
  int pdst[4], psrc[4];
  #pragma unroll
  for (int r = 0; r < 4; r++) {
    pdst[r] = sdst[e0w + quad * 4 + r];
    psrc[r] = ssrc[e0w + quad * 4 + r];
  }
  uint4 hd4[4], hs4[4];
  #pragma unroll
  for (int r = 0; r < 4; r++) {
    hd4[r] = *(const uint4*)(hd_all + (size_t)pdst[r] * 128 + c0);
    hs4[r] = *(const uint4*)(hs_all + (size_t)psrc[r] * 128 + c0);
  }
  asm volatile("" ::: "memory");  // compiler fence: loads cannot sink below

  { // edge-attr features for edge l16 (every lane computes; quad 0 publishes)
    int je = e0w + l16;
    int src = ssrc[je], dst = sdst[je];
    float dx = pos[dst * 3 + 0] - pos[src * 3 + 0];
    float dy = pos[dst * 3 + 1] - pos[src * 3 + 1];
    float dz = pos[dst * 3 + 2] - pos[src * 3 + 2];
    float dist = sqrtf(dx * dx + dy * dy + dz * dz) + 1e-8f;
    float inv = __builtin_amdgcn_rcpf(dist);
    if (quad == 0) {
      s_ea[l16 * 9 + 0] = dist;
      s_ea[l16 * 9 + 1] = dx * inv;
      s_ea[l16 * 9 + 2] = dy * inv;
      s_ea[l16 * 9 + 3] = dz * inv;
      s_ea[l16 * 9 + 4] = __builtin_amdgcn_rcpf(dist * dist + 1e-6f);
    }
    if (l16 == 0) {
      #pragma unroll
      for (int r = 0; r < 4; r++) s_dstw[w][quad * 4 + r] = pdst[r];
    }
  }
  asm volatile("s_waitcnt lgkmcnt(0)" ::: "memory");  // intra-wave LDS publish

  { // phase A: t = hd[dst] + hs[src] + ea@W1c (rank-5, f32); LN+SiLU -> tile
    f32x2 t2a[4][4];
    #pragma unroll
    for (int rr = 0; rr < 4; rr++) {
      u32 hp[4] = {hd4[rr].x, hd4[rr].y, hd4[rr].z, hd4[rr].w};
      u32 sp[4] = {hs4[rr].x, hs4[rr].y, hs4[rr].z, hs4[rr].w};
      #pragma unroll
      for (int p = 0; p < 4; p++)
        t2a[rr][p] = unpk2(hp[p]) + unpk2(sp[p]);
    }
    #pragma unroll
    for (int k = 0; k < 5; k++) {
      f32x4 wa = *(const f32x4*)(w1cF + k * 128 + c0);
      f32x4 wb = *(const f32x4*)(w1cF + k * 128 + c0 + 4);
      f32x2 wk0 = (f32x2){wa[0], wa[1]}, wk1 = (f32x2){wa[2], wa[3]};
      f32x2 wk2 = (f32x2){wb[0], wb[1]}, wk3 = (f32x2){wb[2], wb[3]};
      #pragma unroll
      for (int rr = 0; rr < 4; rr++) {
        float e = s_ea[(quad * 4 + rr) * 9 + k];
        f32x2 ev = (f32x2){e, e};
        t2a[rr][0] += ev * wk0;
        t2a[rr][1] += ev * wk1;
        t2a[rr][2] += ev * wk2;
        t2a[rr][3] += ev * wk3;
      }
    }
    f32x2 g2[4], be2[4];
    {
      f32x4 ga = *(const f32x4*)(g + c0), gb = *(const f32x4*)(g + c0 + 4);
      f32x4 ba = *(const f32x4*)(be + c0), bb = *(const f32x4*)(be + c0 + 4);
      g2[0] = (f32x2){ga[0], ga[1]}; g2[1] = (f32x2){ga[2], ga[3]};
      g2[2] = (f32x2){gb[0], gb[1]}; g2[3] = (f32x2){gb[2], gb[3]};
      be2[0] = (f32x2){ba[0], ba[1]}; be2[1] = (f32x2){ba[2], ba[3]};
      be2[2] = (f32x2){bb[0], bb[1]}; be2[3] = (f32x2){bb[2], bb[3]};
    }
    #pragma unroll
    for (int rr = 0; rr < 4; rr++) {
      f32x2 sm2 = (f32x2){0.f, 0.f}, sq2 = (f32x2){0.f, 0.f};
      #pragma unroll
      for (int p = 0; p < 4; p++) {
        sm2 += t2a[rr][p];
        sq2 += t2a[rr][p] * t2a[rr][p];
      }
      float sm = sm2[0] + sm2[1], sq = sq2[0] + sq2[1];
      sm += __shfl_xor(sm, 1);  sq += __shfl_xor(sq, 1);
      sm += __shfl_xor(sm, 2);  sq += __shfl_xor(sq, 2);
      sm += __shfl_xor(sm, 4);  sq += __shfl_xor(sq, 4);
      sm += __shfl_xor(sm, 8);  sq += __shfl_xor(sq, 8);
      float mean = sm * (1.f / 128.f);
      float rstd = rsq_f(sq * (1.f / 128.f) - mean * mean + 1e-5f);
      f32x2 sc = (f32x2){rstd, rstd};
      f32x2 ofs = (f32x2){-mean * rstd, -mean * rstd};
      float o[8];
      #pragma unroll
      for (int p = 0; p < 4; p++) {
        f32x2 a = t2a[rr][p] * sc + ofs;
        a = a * g2[p] + be2[p];
        o[2 * p]     = silu_f(a[0]);
        o[2 * p + 1] = silu_f(a[1]);
      }
      uint4 st;
      st.x = cvt2bf(o[0], o[1]); st.y = cvt2bf(o[2], o[3]);
      st.z = cvt2bf(o[4], o[5]); st.w = cvt2bf(o[6], o[7]);
      *(uint4*)(tile + (quad * 4 + rr) * AS_STRIDE + c0) = st;
    }
  }

  // ---- per-wave W2 MFMA: 16 rows x 128 cols (8 ct-tiles x 4 kk) --------------
  bf16x8 af[4];
  #pragma unroll
  for (int kk = 0; kk < 4; kk++)
    af[kk] = *(const bf16x8*)(tile + l16 * AS_STRIDE + kk * 32 + quad * 8);

  f32x4 acc[8];
  #pragma unroll
  for (int ct = 0; ct < 8; ct++) acc[ct] = (f32x4){0.f, 0.f, 0.f, 0.f};
  #pragma unroll
  for (int ct = 0; ct < 8; ct++) {
    #pragma unroll
    for (int kk = 0; kk < 4; kk++) {
      bf16x8 bfv = *(const bf16x8*)(W2T + (size_t)(ct * 16 + l16) * 128 + kk * 32 + quad * 8);
      acc[ct] = __builtin_amdgcn_mfma_f32_16x16x32_bf16(af[kk], bfv, acc[ct], 0, 0, 0);
    }
  }

  // ---- pack C col-major into msg [128][20] (aliases tile; af already in regs,
  // and the pack stores are data-dependent on the MFMA results) ----------------
  #pragma unroll
  for (int ct = 0; ct < 8; ct++) {
    int n = ct * 16 + l16;
    uint2 pr;
    pr.x = cvt2bf(acc[ct][0], acc[ct][1]);
    pr.y = cvt2bf(acc[ct][2], acc[ct][3]);
    *(uint2*)(msg + n * 20 + quad * 4) = pr;
  }

  { // per-wave flush: lane handles cols {lane, lane+64} (2-way bank-free)
    int dv[16];
    {
      const int4* dp = (const int4*)&s_dstw[w][0];
      int4 a = dp[0], b = dp[1], c = dp[2], d = dp[3];
      dv[0] = a.x; dv[1] = a.y; dv[2] = a.z; dv[3] = a.w;
      dv[4] = b.x; dv[5] = b.y; dv[6] = b.z; dv[7] = b.w;
      dv[8] = c.x; dv[9] = c.y; dv[10] = c.z; dv[11] = c.w;
      dv[12] = d.x; dv[13] = d.y; dv[14] = d.z; dv[15] = d.w;
    }
    #pragma unroll
    for (int cc = 0; cc < 2; cc++) {
      int n = lane + cc * 64;
      const u16* mp = msg + n * 20;
      uint2 p0 = *(const uint2*)(mp);
      uint2 p1 = *(const uint2*)(mp + 4);
      uint2 p2 = *(const uint2*)(mp + 8);
      uint2 p3 = *(const uint2*)(mp + 12);
      float v[16];
      u32 ws_[8] = {p0.x, p0.y, p1.x, p1.y, p2.x, p2.y, p3.x, p3.y};
      #pragma unroll
      for (int q = 0; q < 8; q++) {
        union { u32 u; float f; } lo, hi;
        lo.u = ws_[q] << 16; hi.u = ws_[q] & 0xffff0000u;
        v[2 * q] = lo.f; v[2 * q + 1] = hi.f;
      }
      float run = 0.f; int cur = dv[0];
      #pragma unroll
      for (int j = 0; j < 16; j++) {
        if (dv[j] != cur) {
          atomicAdd(aggr + (size_t)cur * 128 + n, run);
          run = 0.f; cur = dv[j];
        }
        run += v[j];
      }
      atomicAdd(aggr + (size_t)cur * 128 + n, run);
    }
  }
}

// ------ node MLP + residual + outer LN + fused next hd/hs OR fused decoder ---
__global__ __launch_bounds__(256, 4)
void node_mlp_kernel(u16* __restrict__ hbf, float* __restrict__ aggr,
                     const int* __restrict__ cnt, const float* __restrict__ eb2,
                     const u16* __restrict__ W1T, const float* __restrict__ b1,
                     const float* __restrict__ g, const float* __restrict__ be,
                     const u16* __restrict__ W2T, const float* __restrict__ b2,
                     const float* __restrict__ lng, const float* __restrict__ lnb,
                     const u16* __restrict__ W1Tn, const float* __restrict__ b1n,
                     u16* __restrict__ hd_all, u16* __restrict__ hs_all,
                     const float* __restrict__ x,
                     const u16* __restrict__ dW1T, const float* __restrict__ db1,
                     const u16* __restrict__ dW2T, const float* __restrict__ db2,
                     const u16* __restrict__ dW3T, const float* __restrict__ db3,
                     float* __restrict__ out,
                     int Nn) {
  __shared__ __align__(16) u16 As[128 * AS_STRIDE];  // 34,816 B
  u16* t_su = As;                    // [64][136]
  u16* u_su = As + 64 * AS_STRIDE;   // [64][136]

  const int tid = threadIdx.x;
  const int m0 = blockIdx.x * 64;
  const int w = tid >> 6, lane = tid & 63, quad = lane >> 4, l16 = lane & 15;
  const int c0w = w * 32;

  { // stage h (bf16 copy) + aggr (+cnt*b2e, f32 -> bf16), then zero aggr
    int r = tid >> 4, c8 = (tid & 15) * 8;
    const float4 z4 = {0.f, 0.f, 0.f, 0.f};
    const float4 e0 = *(const float4*)(eb2 + c8);
    const float4 e1 = *(const float4*)(eb2 + c8 + 4);
    #pragma unroll
    for (int rp = 0; rp < 4; rp++) {
      int m = rp * 16 + r;
      int node = m0 + m; if (node >= Nn) node = Nn - 1;
      *(uint4*)(As + m * AS_STRIDE + c8) = *(const uint4*)(hbf + (size_t)node * 128 + c8);
      float* ap = aggr + (size_t)node * 128 + c8;
      float cf = (float)cnt[node];   // aggr_true = aggr + cnt[dst]*b2 (b2 dropped in edge)
      float4 f0 = *(const float4*)ap;
      float4 f1 = *(const float4*)(ap + 4);
      f0.x += cf * e0.x; f0.y += cf * e0.y; f0.z += cf * e0.z; f0.w += cf * e0.w;
      f1.x += cf * e1.x; f1.y += cf * e1.y; f1.z += cf * e1.z; f1.w += cf * e1.w;
      uint4 pk;
      pk.x = cvt2bf(f0.x, f0.y); pk.y = cvt2bf(f0.z, f0.w);
      pk.z = cvt2bf(f1.x, f1.y); pk.w = cvt2bf(f1.z, f1.w);
      *(uint4*)(As + (64 + m) * AS_STRIDE + c8) = pk;
      *(float4*)ap = z4;
      *(float4*)(ap + 4) = z4;
    }
  }
  __syncthreads();

  f32x4 acc[4][2];
  #pragma unroll
  for (int rt = 0; rt < 4; rt++)
    #pragma unroll
    for (int ct = 0; ct < 2; ct++)
      acc[rt][ct] = (f32x4){0.f, 0.f, 0.f, 0.f};

  #pragma unroll
  for (int kk = 0; kk < 8; kk++) {
    const u16* Ab = As + (kk < 4 ? 0 : 64 * AS_STRIDE);
    const int kl = (kk & 3) * 32 + quad * 8;
    bf16x8 af[4];
    #pragma unroll
    for (int rt = 0; rt < 4; rt++)
      af[rt] = *(const bf16x8*)(Ab + (rt * 16 + l16) * AS_STRIDE + kl);
    const int kg = kk * 32 + quad * 8;
    #pragma unroll
    for (int ct = 0; ct < 2; ct++) {
      bf16x8 bfv = *(const bf16x8*)(W1T + (size_t)(c0w + ct * 16 + l16) * 256 + kg);
      #pragma unroll
      for (int rt = 0; rt < 4; rt++)
        acc[rt][ct] = __builtin_amdgcn_mfma_f32_16x16x32_bf16(af[rt], bfv, acc[rt][ct], 0, 0, 0);
    }
  }

  float b1v[2];
  #pragma unroll
  for (int ct = 0; ct < 2; ct++) b1v[ct] = b1[c0w + ct * 16 + l16];
  __syncthreads();

  #pragma unroll
  for (int rt = 0; rt < 4; rt++)
    #pragma unroll
    for (int ct = 0; ct < 2; ct++) {
      int n = c0w + ct * 16 + l16;
      #pragma unroll
      for (int r = 0; r < 4; r++)
        t_su[(rt * 16 + quad * 4 + r) * AS_STRIDE + n] = f2bf1(acc[rt][ct][r] + b1v[ct]);
    }
  __syncthreads();

  { // inner LN + SiLU: read t_su, write u_su
    int row = tid >> 2, sub = tid & 3;
    float s = 0.f, sq = 0.f, vals[32];
    #pragma unroll
    for (int i = 0; i < 32; i++) {
      float v = bf2f(t_su[row * AS_STRIDE + sub + i * 4]);
      vals[i] = v; s += v; sq += v * v;
    }
    s += __shfl_xor(s, 1); sq += __shfl_xor(sq, 1);
    s += __shfl_xor(s, 2); sq += __shfl_xor(sq, 2);
    float mean = s * (1.f / 128.f);
    float rstd = rsq_f(sq * (1.f / 128.f) - mean * mean + 1e-5f);
    #pragma unroll
    for (int i = 0; i < 32; i++) {
      int c = sub + i * 4;
      float a = (vals[i] - mean) * rstd * g[c] + be[c];
      u_su[row * AS_STRIDE + c] = f2bf1(silu_f(a));
    }
  }
  __syncthreads();

  f32x4 acc2[4][2];
  #pragma unroll
  for (int rt = 0; rt < 4; rt++)
    #pragma unroll
    for (int ct = 0; ct < 2; ct++)
      acc2[rt][ct] = (f32x4){0.f, 0.f, 0.f, 0.f};

  #pragma unroll
  for (int kk = 0; kk < 4; kk++) {
    const int kl = kk * 32 + quad * 8;
    bf16x8 af[4];
    #pragma unroll
    for (int rt = 0; rt < 4; rt++)
      af[rt] = *(const bf16x8*)(u_su + (rt * 16 + l16) * AS_STRIDE + kl);
    #pragma unroll
    for (int ct = 0; ct < 2; ct++) {
      bf16x8 bfv = *(const bf16x8*)(W2T + (size_t)(c0w + ct * 16 + l16) * 128 + kl);
      #pragma unroll
      for (int rt = 0; rt < 4; rt++)
        acc2[rt][ct] = __builtin_amdgcn_mfma_f32_16x16x32_bf16(af[rt], bfv, acc2[rt][ct], 0, 0, 0);
    }
  }
  __syncthreads();

  #pragma unroll
  for (int ct = 0; ct < 2; ct++) {
    int n = c0w + ct * 16 + l16;
    float b2v = b2[n];
    #pragma unroll
    for (int rt = 0; rt < 4; rt++)
      #pragma unroll
      for (int r = 0; r < 4; r++) {
        int m = rt * 16 + quad * 4 + r;
        int node = m0 + m; if (node >= Nn) node = Nn - 1;
        t_su[m * AS_STRIDE + n] =
            f2bf1(acc2[rt][ct][r] + b2v + bf2f(hbf[(size_t)node * 128 + n]));
      }
  }
  __syncthreads();

  { // outer LN -> hbf and back into t_su (A-layout h)
    int row = tid >> 2, sub = tid & 3;
    int node = m0 + row;
    float s = 0.f, sq = 0.f, vals[32];
    #pragma unroll
    for (int i = 0; i < 32; i++) {
      float v = bf2f(t_su[row * AS_STRIDE + sub + i * 4]);
      vals[i] = v; s += v; sq += v * v;
    }
    s += __shfl_xor(s, 1); sq += __shfl_xor(sq, 1);
    s += __shfl_xor(s, 2); sq += __shfl_xor(sq, 2);
    float mean = s * (1.f / 128.f);
    float rstd = rsq_f(sq * (1.f / 128.f) - mean * mean + 1e-5f);
    #pragma unroll
    for (int i = 0; i < 32; i++) {
      int c = sub + i * 4;
      float v = (vals[i] - mean) * rstd * lng[c] + lnb[c];
      u16 hb = f2bf1(v);
      t_su[row * AS_STRIDE + c] = hb;
      if (node < Nn) hbf[(size_t)node * 128 + c] = hb;
    }
  }

  if (W1Tn != nullptr) { // fused next-layer hd = h@W1d + b1, hs = h@W1s
    __syncthreads();
    f32x4 ah[4][2];
    #pragma unroll
    for (int rt = 0; rt < 4; rt++)
      #pragma unroll
      for (int ct = 0; ct < 2; ct++)
        ah[rt][ct] = (f32x4){0.f, 0.f, 0.f, 0.f};
    #pragma unroll
    for (int kk = 0; kk < 4; kk++) {
      const int kl = kk * 32 + quad * 8;
      bf16x8 af[4];
      #pragma unroll
      for (int rt = 0; rt < 4; rt++)
        af[rt] = *(const bf16x8*)(t_su + (rt * 16 + l16) * AS_STRIDE + kl);
      #pragma unroll
      for (int ct = 0; ct < 2; ct++) {
        bf16x8 bd = *(const bf16x8*)(W1Tn + (size_t)(c0w + ct * 16 + l16) * 256 + kl);
        #pragma unroll
        for (int rt = 0; rt < 4; rt++)
          ah[rt][ct] = __builtin_amdgcn_mfma_f32_16x16x32_bf16(af[rt], bd, ah[rt][ct], 0, 0, 0);
      }
    }
    #pragma unroll
    for (int ct = 0; ct < 2; ct++) {
      int n = c0w + ct * 16 + l16;
      float bv = b1n[n];
      #pragma unroll
      for (int rt = 0; rt < 4; rt++)
        #pragma unroll
        for (int r = 0; r < 4; r++) {
          int node = m0 + rt * 16 + quad * 4 + r;
          if (node < Nn) hd_all[(size_t)node * 128 + n] = f2bf1(ah[rt][ct][r] + bv);
        }
    }
    #pragma unroll
    for (int rt = 0; rt < 4; rt++)
      #pragma unroll
      for (int ct = 0; ct < 2; ct++)
        ah[rt][ct] = (f32x4){0.f, 0.f, 0.f, 0.f};
    #pragma unroll
    for (int kk = 0; kk < 4; kk++) {
      const int kl = kk * 32 + quad * 8;
      bf16x8 af[4];
      #pragma unroll
      for (int rt = 0; rt < 4; rt++)
        af[rt] = *(const bf16x8*)(t_su + (rt * 16 + l16) * AS_STRIDE + kl);
      #pragma unroll
      for (int ct = 0; ct < 2; ct++) {
        bf16x8 bs = *(const bf16x8*)(W1Tn + (size_t)(c0w + ct * 16 + l16) * 256 + 128 + kl);
        #pragma unroll
        for (int rt = 0; rt < 4; rt++)
          ah[rt][ct] = __builtin_amdgcn_mfma_f32_16x16x32_bf16(af[rt], bs, ah[rt][ct], 0, 0, 0);
      }
    }
    #pragma unroll
    for (int ct = 0; ct < 2; ct++) {
      int n = c0w + ct * 16 + l16;
      #pragma unroll
      for (int rt = 0; rt < 4; rt++)
        #pragma unroll
        for (int r = 0; r < 4; r++) {
          int node = m0 + rt * 16 + quad * 4 + r;
          if (node < Nn) hs_all[(size_t)node * 128 + n] = f2bf1(ah[rt][ct][r]);
        }
    }
  }

  if (dW1T != nullptr) { // fused decoder (layer 2): h in t_su (A-layout)
    __syncthreads();
    f32x4 da[4][2];
    #pragma unroll
    for (int rt = 0; rt < 4; rt++)
      #pragma unroll
      for (int ct = 0; ct < 2; ct++)
        da[rt][ct] = (f32x4){0.f, 0.f, 0.f, 0.f};
    #pragma unroll
    for (int kk = 0; kk < 4; kk++) {
      const int kl = kk * 32 + quad * 8;
      bf16x8 af[4];
      #pragma unroll
      for (int rt = 0; rt < 4; rt++)
        af[rt] = *(const bf16x8*)(t_su + (rt * 16 + l16) * AS_STRIDE + kl);
      #pragma unroll
      for (int ct = 0; ct < 2; ct++) {
        bf16x8 bfv = *(const bf16x8*)(dW1T + (size_t)(c0w + ct * 16 + l16) * 128 + kl);
        #pragma unroll
        for (int rt = 0; rt < 4; rt++)
          da[rt][ct] = __builtin_amdgcn_mfma_f32_16x16x32_bf16(af[rt], bfv, da[rt][ct], 0, 0, 0);
      }
    }
    __syncthreads();
    #pragma unroll
    for (int ct = 0; ct < 2; ct++) {
      int n = c0w + ct * 16 + l16;
      float bv = db1[n];
      #pragma unroll
      for (int rt = 0; rt < 4; rt++)
        #pragma unroll
        for (int r = 0; r < 4; r++)
          u_su[(rt * 16 + quad * 4 + r) * AS_STRIDE + n] = f2bf1(silu_f(da[rt][ct][r] + bv));
    }
    __syncthreads();
    { // dec L2: 64 cols, wave covers 16; u2 overwrites t_su region
      const int c0b = w * 16;
      f32x4 a2[4];
      #pragma unroll
      for (int rt = 0; rt < 4; rt++) a2[rt] = (f32x4){0.f, 0.f, 0.f, 0.f};
      #pragma unroll
      for (int kk = 0; kk < 4; kk++) {
        const int kl = kk * 32 + quad * 8;
        bf16x8 af[4];
        #pragma unroll
        for (int rt = 0; rt < 4; rt++)
          af[rt] = *(const bf16x8*)(u_su + (rt * 16 + l16) * AS_STRIDE + kl);
        bf16x8 bfv = *(const bf16x8*)(dW2T + (size_t)(c0b + l16) * 128 + kl);
        #pragma unroll
        for (int rt = 0; rt < 4; rt++)
          a2[rt] = __builtin_amdgcn_mfma_f32_16x16x32_bf16(af[rt], bfv, a2[rt], 0, 0, 0);
      }
      float bv = db2[c0b + l16];
      #pragma unroll
      for (int rt = 0; rt < 4; rt++)
        #pragma unroll
        for (int r = 0; r < 4; r++)
          t_su[(rt * 16 + quad * 4 + r) * 72 + c0b + l16] = f2bf1(silu_f(a2[rt][r] + bv));
    }
    __syncthreads();
    if (w == 0) { // dec L3: 6 cols (padded 16), K=64
      f32x4 a3[4];
      #pragma unroll
      for (int rt = 0; rt < 4; rt++) a3[rt] = (f32x4){0.f, 0.f, 0.f, 0.f};
      #pragma unroll
      for (int kk = 0; kk < 2; kk++) {
        const int kl = kk * 32 + quad * 8;
        bf16x8 af[4];
        #pragma unroll
        for (int rt = 0; rt < 4; rt++)
          af[rt] = *(const bf16x8*)(t_su + (rt * 16 + l16) * 72 + kl);
        bf16x8 bfv = *(const bf16x8*)(dW3T + l16 * 64 + kl);
        #pragma unroll
        for (int rt = 0; rt < 4; rt++)
          a3[rt] = __builtin_amdgcn_mfma_f32_16x16x32_bf16(af[rt], bfv, a3[rt], 0, 0, 0);
      }
      if (l16 < 6) {
        float bv = db3[l16];
        #pragma unroll
        for (int rt = 0; rt < 4; rt++)
          #pragma unroll
          for (int r = 0; r < 4; r++) {
            int node = m0 + rt * 16 + quad * 4 + r;
            if (node < Nn)
              out[(size_t)node * 6 + l16] = a3[rt][r] + bv + x[node * 7 + l16];
          }
      }
    }
  }
}

// ---------------- host launcher ----------------------------------------------
extern "C" void kernel_launch(void* const* d_in, const int* in_sizes, int n_in,
                              void* d_out, int out_size, void* d_ws, size_t ws_size,
                              hipStream_t stream) {
  const float* x      = (const float*)d_in[0];
  const float* pos    = (const float*)d_in[1];
  const int*   eidx   = (const int*)d_in[2];
  const float* enc_w1 = (const float*)d_in[3];
  const float* enc_b1 = (const float*)d_in[4];
  const float* enc_g  = (const float*)d_in[5];
  const float* enc_be = (const float*)d_in[6];
  const float* enc_w2 = (const float*)d_in[7];
  const float* enc_b2 = (const float*)d_in[8];
  const float* e_w1   = (const float*)d_in[9];
  const float* e_b1   = (const float*)d_in[10];
  const float* e_g    = (const float*)d_in[11];
  const float* e_be   = (const float*)d_in[12];
  const float* e_w2   = (const float*)d_in[13];
  const float* e_b2   = (const float*)d_in[14];
  const float* n_w1   = (const float*)d_in[15];
  const float* n_b1   = (const float*)d_in[16];
  const float* n_g    = (const float*)d_in[17];
  const float* n_be   = (const float*)d_in[18];
  const float* n_w2   = (const float*)d_in[19];
  const float* n_b2   = (const float*)d_in[20];
  const float* ln_g   = (const float*)d_in[21];
  const float* ln_b   = (const float*)d_in[22];
  const float* dec_w1 = (const float*)d_in[23];
  const float* dec_b1 = (const float*)d_in[24];
  const float* dec_w2 = (const float*)d_in[25];
  const float* dec_b2 = (const float*)d_in[26];
  const float* dec_w3 = (const float*)d_in[27];
  const float* dec_b3 = (const float*)d_in[28];

  const int N = in_sizes[0] / 7;          // 50000
  const int E = in_sizes[2] / 2;          // 1600000

  char* ws = (char*)d_ws;
  size_t off = 0;
  u16*   hbf    = (u16*)(ws + off);   off += (size_t)N * 128 * 2;
  u16*   hd_all = (u16*)(ws + off);   off += (size_t)N * 128 * 2;
  u16*   hs_all = (u16*)(ws + off);   off += (size_t)N * 128 * 2;
  float* aggr   = (float*)(ws + off); off += (size_t)N * 128 * 4;
  u16* eW1T = (u16*)(ws + off); off += 3 * 128 * 256 * 2;
  u16* eW2T = (u16*)(ws + off); off += 3 * 128 * 128 * 2;
  u16* nW1T = (u16*)(ws + off); off += 3 * 128 * 256 * 2;
  u16* nW2T = (u16*)(ws + off); off += 3 * 128 * 128 * 2;
  u16* encW1T = (u16*)(ws + off); off += 128 * 32 * 2;
  u16* encW2T = (u16*)(ws + off); off += 128 * 128 * 2;
  u16* decW1T = (u16*)(ws + off); off += 128 * 128 * 2;
  u16* decW2T = (u16*)(ws + off); off += 64 * 128 * 2;
  u16* decW3T = (u16*)(ws + off); off += 16 * 64 * 2;
  int* cnt    = (int*)(ws + off); off += (size_t)N * 4;
  int* cursor = (int*)(ws + off); off += (size_t)N * 4;
  int* ssrc   = (int*)(ws + off); off += (size_t)E * 4;
  int* sdst   = (int*)(ws + off); off += (size_t)E * 4;

  // sort edges by dst once (reused across all 3 layers); cnt preserved for node
  hipMemsetAsync(cnt, 0, (size_t)N * 4, stream);
  edge_hist<<<(E + 255) / 256, 256, 0, stream>>>(eidx + E, E, cnt);
  scan_kernel<<<1, 1024, 0, stream>>>(cnt, cursor, N);
  edge_scatter<<<(E + 255) / 256, 256, 0, stream>>>(eidx, eidx + E, E, cursor, ssrc, sdst);

  prep_weights<<<1152, 256, 0, stream>>>(e_w1, e_w2, n_w1, n_w2, eW1T, eW2T, nW1T, nW2T);
  prep_weights2<<<180, 256, 0, stream>>>(enc_w1, enc_w2, dec_w1, dec_w2, dec_w3,
                                         encW1T, encW2T, decW1T, decW2T, decW3T);

  // zero aggr ONCE; node_mlp re-zeroes its rows for the next layer after reading
  hipMemsetAsync(aggr, 0, (size_t)N * 128 * 4, stream);

  const int nblk = (N + 63) / 64;
  encoder_mfma<<<nblk, 256, 0, stream>>>(x, encW1T, enc_b1, enc_g, enc_be, encW2T, enc_b2,
                                         eW1T, e_b1, hbf, hd_all, hs_all, N);

  for (int l = 0; l < 3; l++) {
    edge_mlp_kernel<<<E / 64, 256, 0, stream>>>(
        ssrc, sdst, pos, hd_all, hs_all,
        e_w1 + (size_t)l * 33408 + 256 * 128,   // W1c rows as f32 [5][128]
        e_g + l * 128, e_be + l * 128,
        eW2T + (size_t)l * 128 * 128, aggr);
    const u16* W1Tn = (l < 2) ? (eW1T + (size_t)(l + 1) * 128 * 256) : (const u16*)nullptr;
    const bool last = (l == 2);
    node_mlp_kernel<<<nblk, 256, 0, stream>>>(
        hbf, aggr, cnt, e_b2 + l * 128,
        nW1T + (size_t)l * 128 * 256, n_b1 + l * 128, n_g + l * 128, n_be + l * 128,
        nW2T + (size_t)l * 128 * 128, n_b2 + l * 128,
        ln_g + l * 128, ln_b + l * 128,
        W1Tn, e_b1 + ((l + 1) % 3) * 128, hd_all, hs_all,
        x,
        last ? decW1T : (const u16*)nullptr, dec_b1,
        last ? decW2T : (const u16*)nullptr, dec_b2,
        last ? decW3T : (const u16*)nullptr, dec_b3,
        (float*)d_out, N);
  }
}

// Round 8
// 1165.467 us; speedup vs baseline: 1.6616x; 1.6616x over previous
//
#include <hip/hip_runtime.h>

typedef unsigned short u16;
typedef unsigned int u32;
typedef __bf16 bf16x8 __attribute__((ext_vector_type(8)));
typedef float f32x4 __attribute__((ext_vector_type(4)));
typedef float f32x2 __attribute__((ext_vector_type(2)));

#define AS_STRIDE 136   // bf16 elems per LDS A-row (128 + 8 pad; 16B-aligned rows)

__device__ __forceinline__ u16 f2bf1(float f) {
  union { __bf16 h; u16 u; } c; c.h = (__bf16)f; return c.u;
}
__device__ __forceinline__ u32 cvt2bf(float a, float b) {
  union { __bf16 h[2]; u32 u; } c; c.h[0] = (__bf16)a; c.h[1] = (__bf16)b; return c.u;
}
__device__ __forceinline__ float bf2f(u16 u) {
  union { u32 u; float f; } v; v.u = ((u32)u) << 16; return v.f;
}
// silu via v_rcp_f32 (2 ops) instead of IEEE f32 divide (~10-op sequence)
__device__ __forceinline__ float silu_f(float a) {
  return a * __builtin_amdgcn_rcpf(1.f + __expf(-a));
}
__device__ __forceinline__ float rsq_f(float x) {
  return __builtin_amdgcn_rsqf(x);
}
__device__ __forceinline__ f32x2 unpk2(u32 p) {
  union { u32 u; float f; } a, b;
  a.u = p << 16; b.u = p & 0xffff0000u;
  return (f32x2){a.f, b.f};
}
// involution mapping LDS row -> sorted-edge index: swaps the rt and quad fields
// P(rt*16 + quad*4 + r) = quad*16 + rt*4 + r  (P(P(i)) == i)
__device__ __forceinline__ int permP(int i) {
  return ((i >> 2) & 3) * 16 + ((i >> 4) & 3) * 4 + (i & 3);
}

// ---------------- edge sort by dst (counting sort, once per call) ------------
__global__ void edge_hist(const int* __restrict__ edst, int E, int* __restrict__ cnt) {
  int i = blockIdx.x * blockDim.x + threadIdx.x;
  if (i < E) atomicAdd(&cnt[edst[i]], 1);
}

__global__ __launch_bounds__(1024)
void scan_kernel(const int* __restrict__ cnt, int* __restrict__ cursor, int Nn) {
  __shared__ int part[1024];
  int t = threadIdx.x;
  int per = (Nn + 1023) / 1024;
  int b = t * per;
  int s = 0;
  for (int i = 0; i < per; i++) { int idx = b + i; if (idx < Nn) s += cnt[idx]; }
  part[t] = s;
  __syncthreads();
  for (int d = 1; d < 1024; d <<= 1) {
    int v = (t >= d) ? part[t - d] : 0;
    __syncthreads();
    part[t] += v;
    __syncthreads();
  }
  int excl = (t == 0) ? 0 : part[t - 1];
  for (int i = 0; i < per; i++) {
    int idx = b + i;
    if (idx < Nn) { cursor[idx] = excl; excl += cnt[idx]; }
  }
}

// r11: single int2 store per edge (was 2x4B to two regions) -> halves the
// scattered-HBM-line count of the sort (r7 counters: scatter WRITE ~145MB).
__global__ void edge_scatter(const int* __restrict__ esrc, const int* __restrict__ edst,
                             int E, int* __restrict__ cursor,
                             int2* __restrict__ sedge) {
  int i = blockIdx.x * blockDim.x + threadIdx.x;
  if (i < E) {
    int d = edst[i];
    int p = atomicAdd(&cursor[d], 1);
    sedge[p] = make_int2(esrc[i], d);
  }
}

// ---------------- weight prep: transpose + bf16-cast -------------------------
__global__ void prep_weights(const float* __restrict__ e_w1, const float* __restrict__ e_w2,
                             const float* __restrict__ n_w1, const float* __restrict__ n_w2,
                             u16* __restrict__ eW1T, u16* __restrict__ eW2T,
                             u16* __restrict__ nW1T, u16* __restrict__ nW2T) {
  int i = blockIdx.x * blockDim.x + threadIdx.x;
  const int s1 = 3 * 128 * 256;
  const int s2 = 3 * 128 * 128;
  if (i < s1) {
    int l = i / 32768, r = i % 32768, n = r >> 8, k = r & 255;
    eW1T[i] = f2bf1(e_w1[l * 33408 + k * 128 + n]);
  } else if (i < s1 + s2) {
    int j = i - s1; int l = j / 16384, r = j % 16384, n = r >> 7, k = r & 127;
    eW2T[j] = f2bf1(e_w2[l * 16384 + k * 128 + n]);
  } else if (i < s1 + s2 + s1) {
    int j = i - s1 - s2; int l = j / 32768, r = j % 32768, n = r >> 8, k = r & 255;
    nW1T[j] = f2bf1(n_w1[l * 32768 + k * 128 + n]);
  } else if (i < 2 * s1 + 2 * s2) {
    int j = i - 2 * s1 - s2; int l = j / 16384, r = j % 16384, n = r >> 7, k = r & 127;
    nW2T[j] = f2bf1(n_w2[l * 16384 + k * 128 + n]);
  }
}

// enc/dec weights (edge-attr weight consumed as f32 directly from e_w1)
__global__ void prep_weights2(const float* __restrict__ enc_w1, const float* __restrict__ enc_w2,
                              const float* __restrict__ dec_w1, const float* __restrict__ dec_w2,
                              const float* __restrict__ dec_w3,
                              u16* __restrict__ encW1T, u16* __restrict__ encW2T,
                              u16* __restrict__ decW1T, u16* __restrict__ decW2T,
                              u16* __restrict__ decW3T) {
  int i = blockIdx.x * blockDim.x + threadIdx.x;
  if (i < 4096) {
    int n = i >> 5, k = i & 31;
    encW1T[i] = (k < 7) ? f2bf1(enc_w1[k * 128 + n]) : (u16)0;
  } else if (i < 20480) {
    int j = i - 4096; int n = j >> 7, k = j & 127;
    encW2T[j] = f2bf1(enc_w2[k * 128 + n]);
  } else if (i < 36864) {
    int j = i - 20480; int n = j >> 7, k = j & 127;
    decW1T[j] = f2bf1(dec_w1[k * 128 + n]);
  } else if (i < 45056) {
    int j = i - 36864; int n = j >> 7, k = j & 127;
    decW2T[j] = f2bf1(dec_w2[k * 64 + n]);
  } else if (i < 46080) {
    int j = i - 45056; int n = j >> 6, k = j & 63;
    decW3T[j] = (n < 6) ? f2bf1(dec_w3[k * 6 + n]) : (u16)0;
  }
}

// ---------------- encoder (MFMA) + fused hd/hs for layer 0 -------------------
__global__ __launch_bounds__(256, 4)
void encoder_mfma(const float* __restrict__ x,
                  const u16* __restrict__ W1T,   // [128][32]
                  const float* __restrict__ b1,
                  const float* __restrict__ g, const float* __restrict__ be,
                  const u16* __restrict__ W2T,   // [128][128]
                  const float* __restrict__ b2,
                  const u16* __restrict__ eW1T0, // [128][256] layer-0 edge W1
                  const float* __restrict__ eb10,
                  u16* __restrict__ hbf, u16* __restrict__ hd_all,
                  u16* __restrict__ hs_all, int Nn) {
  __shared__ __align__(16) u16 As[64 * 40];
  __shared__ __align__(16) u16 ts[64 * AS_STRIDE];
  const int tid = threadIdx.x;
  const int m0 = blockIdx.x * 64;
  const int w = tid >> 6, lane = tid & 63, quad = lane >> 4, l16 = lane & 15;
  const int c0w = w * 32;

  if (tid < 64) {
    int node = m0 + tid; if (node >= Nn) node = Nn - 1;
    union { u16 us[32]; uint4 v[4]; } pk;
    #pragma unroll
    for (int k = 0; k < 32; k++) pk.us[k] = 0;
    #pragma unroll
    for (int k = 0; k < 7; k++) pk.us[k] = f2bf1(x[node * 7 + k]);
    #pragma unroll
    for (int k = 0; k < 4; k++) *(uint4*)(As + tid * 40 + k * 8) = pk.v[k];
  }
  __syncthreads();

  f32x4 acc[4][2];
  #pragma unroll
  for (int rt = 0; rt < 4; rt++)
    #pragma unroll
    for (int ct = 0; ct < 2; ct++)
      acc[rt][ct] = (f32x4){0.f, 0.f, 0.f, 0.f};
  {
    const int kl = quad * 8;
    bf16x8 af[4];
    #pragma unroll
    for (int rt = 0; rt < 4; rt++)
      af[rt] = *(const bf16x8*)(As + (rt * 16 + l16) * 40 + kl);
    #pragma unroll
    for (int ct = 0; ct < 2; ct++) {
      bf16x8 bfv = *(const bf16x8*)(W1T + (c0w + ct * 16 + l16) * 32 + kl);
      #pragma unroll
      for (int rt = 0; rt < 4; rt++)
        acc[rt][ct] = __builtin_amdgcn_mfma_f32_16x16x32_bf16(af[rt], bfv, acc[rt][ct], 0, 0, 0);
    }
  }
  #pragma unroll
  for (int ct = 0; ct < 2; ct++) {
    int n = c0w + ct * 16 + l16;
    float b1v = b1[n];
    #pragma unroll
    for (int rt = 0; rt < 4; rt++)
      #pragma unroll
      for (int r = 0; r < 4; r++)
        ts[(rt * 16 + quad * 4 + r) * AS_STRIDE + n] = f2bf1(acc[rt][ct][r] + b1v);
  }
  __syncthreads();

  { // LN + SiLU in place (bf16)
    int row = tid >> 2, sub = tid & 3;
    float s = 0.f, sq = 0.f, vals[32];
    #pragma unroll
    for (int i = 0; i < 32; i++) {
      float v = bf2f(ts[row * AS_STRIDE + sub + i * 4]);
      vals[i] = v; s += v; sq += v * v;
    }
    s += __shfl_xor(s, 1); sq += __shfl_xor(sq, 1);
    s += __shfl_xor(s, 2); sq += __shfl_xor(sq, 2);
    float mean = s * (1.f / 128.f);
    float rstd = rsq_f(sq * (1.f / 128.f) - mean * mean + 1e-5f);
    #pragma unroll
    for (int i = 0; i < 32; i++) {
      int c = sub + i * 4;
      float a = (vals[i] - mean) * rstd * g[c] + be[c];
      ts[row * AS_STRIDE + c] = f2bf1(silu_f(a));
    }
  }
  __syncthreads();

  f32x4 acc2[4][2];
  #pragma unroll
  for (int rt = 0; rt < 4; rt++)
    #pragma unroll
    for (int ct = 0; ct < 2; ct++)
      acc2[rt][ct] = (f32x4){0.f, 0.f, 0.f, 0.f};
  #pragma unroll
  for (int kk = 0; kk < 4; kk++) {
    const int kl = kk * 32 + quad * 8;
    bf16x8 af[4];
    #pragma unroll
    for (int rt = 0; rt < 4; rt++)
      af[rt] = *(const bf16x8*)(ts + (rt * 16 + l16) * AS_STRIDE + kl);
    #pragma unroll
    for (int ct = 0; ct < 2; ct++) {
      bf16x8 bfv = *(const bf16x8*)(W2T + (size_t)(c0w + ct * 16 + l16) * 128 + kl);
      #pragma unroll
      for (int rt = 0; rt < 4; rt++)
        acc2[rt][ct] = __builtin_amdgcn_mfma_f32_16x16x32_bf16(af[rt], bfv, acc2[rt][ct], 0, 0, 0);
    }
  }
  __syncthreads();   // ts reads done; rewrite with h
  #pragma unroll
  for (int ct = 0; ct < 2; ct++) {
    int n = c0w + ct * 16 + l16;
    float b2v = b2[n];
    #pragma unroll
    for (int rt = 0; rt < 4; rt++)
      #pragma unroll
      for (int r = 0; r < 4; r++) {
        int m = rt * 16 + quad * 4 + r;
        int node = m0 + m;
        u16 hb = f2bf1(acc2[rt][ct][r] + b2v);
        ts[m * AS_STRIDE + n] = hb;
        if (node < Nn) hbf[(size_t)node * 128 + n] = hb;
      }
  }
  __syncthreads();

  { // fused hd = h@W1d + b1, then hs = h@W1s (layer 0)
    f32x4 ah[4][2];
    #pragma unroll
    for (int rt = 0; rt < 4; rt++)
      #pragma unroll
      for (int ct = 0; ct < 2; ct++)
        ah[rt][ct] = (f32x4){0.f, 0.f, 0.f, 0.f};
    #pragma unroll
    for (int kk = 0; kk < 4; kk++) {
      const int kl = kk * 32 + quad * 8;
      bf16x8 af[4];
      #pragma unroll
      for (int rt = 0; rt < 4; rt++)
        af[rt] = *(const bf16x8*)(ts + (rt * 16 + l16) * AS_STRIDE + kl);
      #pragma unroll
      for (int ct = 0; ct < 2; ct++) {
        bf16x8 bd = *(const bf16x8*)(eW1T0 + (size_t)(c0w + ct * 16 + l16) * 256 + kl);
        #pragma unroll
        for (int rt = 0; rt < 4; rt++)
          ah[rt][ct] = __builtin_amdgcn_mfma_f32_16x16x32_bf16(af[rt], bd, ah[rt][ct], 0, 0, 0);
      }
    }
    #pragma unroll
    for (int ct = 0; ct < 2; ct++) {
      int n = c0w + ct * 16 + l16;
      float b1v = eb10[n];
      #pragma unroll
      for (int rt = 0; rt < 4; rt++)
        #pragma unroll
        for (int r = 0; r < 4; r++) {
          int node = m0 + rt * 16 + quad * 4 + r;
          if (node < Nn) hd_all[(size_t)node * 128 + n] = f2bf1(ah[rt][ct][r] + b1v);
        }
    }
    #pragma unroll
    for (int rt = 0; rt < 4; rt++)
      #pragma unroll
      for (int ct = 0; ct < 2; ct++)
        ah[rt][ct] = (f32x4){0.f, 0.f, 0.f, 0.f};
    #pragma unroll
    for (int kk = 0; kk < 4; kk++) {
      const int kl = kk * 32 + quad * 8;
      bf16x8 af[4];
      #pragma unroll
      for (int rt = 0; rt < 4; rt++)
        af[rt] = *(const bf16x8*)(ts + (rt * 16 + l16) * AS_STRIDE + kl);
      #pragma unroll
      for (int ct = 0; ct < 2; ct++) {
        bf16x8 bs = *(const bf16x8*)(eW1T0 + (size_t)(c0w + ct * 16 + l16) * 256 + 128 + kl);
        #pragma unroll
        for (int rt = 0; rt < 4; rt++)
          ah[rt][ct] = __builtin_amdgcn_mfma_f32_16x16x32_bf16(af[rt], bs, ah[rt][ct], 0, 0, 0);
      }
    }
    #pragma unroll
    for (int ct = 0; ct < 2; ct++) {
      int n = c0w + ct * 16 + l16;
      #pragma unroll
      for (int rt = 0; rt < 4; rt++)
        #pragma unroll
        for (int r = 0; r < 4; r++) {
          int node = m0 + rt * 16 + quad * 4 + r;
          if (node < Nn) hs_all[(size_t)node * 128 + n] = f2bf1(ah[rt][ct][r]);
        }
    }
  }
}

// ---------------- edge MLP: rank-5 ea term in registers (r9 structure) -------
// r11 = r9 (verified 210us) + int2 edge reads + b2 folded to node via cnt.
// r10 lesson: wave-private W2 MFMA quadruples B-operand traffic -> keep the
// 4-wave shared tile with 2 barriers (each wave reads only its 32 W2 columns).
__global__ __launch_bounds__(256, 6)
void edge_mlp_kernel(const int2* __restrict__ sedge,
                     const float* __restrict__ pos,
                     const u16* __restrict__ hd_all, const u16* __restrict__ hs_all,
                     const float* __restrict__ w1cF, // [5][128] f32 (= e_w1 rows 256..260)
                     const float* __restrict__ g, const float* __restrict__ be,
                     const u16* __restrict__ W2T,   // [128][128] bf16
                     float* __restrict__ aggr) {
  __shared__ int s_dst[64];                           // dst of SORTED edge e0+i
  __shared__ __align__(16) float s_ea[64 * 8];        // ea feats f32, row i = edge P(i)
  __shared__ __align__(16) float s_w1c[5 * 128];      // W1c f32
  __shared__ __align__(16) u16 s_t[64 * AS_STRIDE];   // u (row i = edge P(i))
  // LDS total 22272 B -> 6 blocks/CU (the r2 sweet spot)

  const int tid = threadIdx.x;
  // XCD swizzle: consecutive-dst chunks stay on one XCD
  const int bid = blockIdx.x;
  const int e0 = ((bid & 7) * (gridDim.x >> 3) + (bid >> 3)) * 64;
  const int w = tid >> 6, lane = tid & 63, quad = lane >> 4, l16 = lane & 15;
  const int c0w = w * 32;
  const int rg = tid >> 4, cg = tid & 15;
  const int c0 = cg * 8;

  // ---- prefetch ALL phase-A gathers at kernel top; fence pins issue order ----
  int pdst[4], psrc[4];
  #pragma unroll
  for (int rr = 0; rr < 4; rr++) {
    int j = permP(rg * 4 + rr);          // LDS row rg*4+rr holds edge e0+P(row)
    int2 e = sedge[e0 + j];
    psrc[rr] = e.x;
    pdst[rr] = e.y;
  }
  uint4 hd4[4], hs4[4];
  #pragma unroll
  for (int rr = 0; rr < 4; rr++) {
    hd4[rr] = *(const uint4*)(hd_all + (size_t)pdst[rr] * 128 + c0);
    hs4[rr] = *(const uint4*)(hs_all + (size_t)psrc[rr] * 128 + c0);
  }
  asm volatile("" ::: "memory");  // compiler fence: loads cannot sink below

  if (tid < 64) {
    int jp = permP(tid);
    int2 ej = sedge[e0 + jp];
    int src = ej.x, dst = ej.y;
    s_dst[tid] = sedge[e0 + tid].y;       // sorted order, for the atomic flush
    float dx = pos[dst * 3 + 0] - pos[src * 3 + 0];
    float dy = pos[dst * 3 + 1] - pos[src * 3 + 1];
    float dz = pos[dst * 3 + 2] - pos[src * 3 + 2];
    float dist = sqrtf(dx * dx + dy * dy + dz * dz) + 1e-8f;
    float inv = __builtin_amdgcn_rcpf(dist);
    s_ea[tid * 8 + 0] = dist;
    s_ea[tid * 8 + 1] = dx * inv;
    s_ea[tid * 8 + 2] = dy * inv;
    s_ea[tid * 8 + 3] = dz * inv;
    s_ea[tid * 8 + 4] = __builtin_amdgcn_rcpf(dist * dist + 1e-6f);
  }
  if (tid < 160) *(float4*)(s_w1c + tid * 4) = *(const float4*)(w1cF + tid * 4);
  __syncthreads();

  { // phase A: t = hd[dst] + hs[src] + ea@W1c (rank-5, f32); LN+SiLU -> u in s_t
    f32x2 t2a[4][4];
    #pragma unroll
    for (int rr = 0; rr < 4; rr++) {
      u32 hp[4] = {hd4[rr].x, hd4[rr].y, hd4[rr].z, hd4[rr].w};
      u32 sp[4] = {hs4[rr].x, hs4[rr].y, hs4[rr].z, hs4[rr].w};
      #pragma unroll
      for (int p = 0; p < 4; p++)
        t2a[rr][p] = unpk2(hp[p]) + unpk2(sp[p]);
    }
    #pragma unroll
    for (int k = 0; k < 5; k++) {
      f32x4 wa = *(const f32x4*)(s_w1c + k * 128 + c0);
      f32x4 wb = *(const f32x4*)(s_w1c + k * 128 + c0 + 4);
      f32x2 wk0 = (f32x2){wa[0], wa[1]}, wk1 = (f32x2){wa[2], wa[3]};
      f32x2 wk2 = (f32x2){wb[0], wb[1]}, wk3 = (f32x2){wb[2], wb[3]};
      #pragma unroll
      for (int rr = 0; rr < 4; rr++) {
        float e = s_ea[(rg * 4 + rr) * 8 + k];
        f32x2 ev = (f32x2){e, e};
        t2a[rr][0] += ev * wk0;
        t2a[rr][1] += ev * wk1;
        t2a[rr][2] += ev * wk2;
        t2a[rr][3] += ev * wk3;
      }
    }
    f32x2 g2[4], be2[4];
    {
      f32x4 ga = *(const f32x4*)(g + c0), gb = *(const f32x4*)(g + c0 + 4);
      f32x4 ba = *(const f32x4*)(be + c0), bb = *(const f32x4*)(be + c0 + 4);
      g2[0] = (f32x2){ga[0], ga[1]}; g2[1] = (f32x2){ga[2], ga[3]};
      g2[2] = (f32x2){gb[0], gb[1]}; g2[3] = (f32x2){gb[2], gb[3]};
      be2[0] = (f32x2){ba[0], ba[1]}; be2[1] = (f32x2){ba[2], ba[3]};
      be2[2] = (f32x2){bb[0], bb[1]}; be2[3] = (f32x2){bb[2], bb[3]};
    }
    #pragma unroll
    for (int rr = 0; rr < 4; rr++) {
      int m = rg * 4 + rr;
      f32x2 sm2 = (f32x2){0.f, 0.f}, sq2 = (f32x2){0.f, 0.f};
      #pragma unroll
      for (int p = 0; p < 4; p++) {
        sm2 += t2a[rr][p];
        sq2 += t2a[rr][p] * t2a[rr][p];
      }
      float sm = sm2[0] + sm2[1], sq = sq2[0] + sq2[1];
      sm += __shfl_xor(sm, 1);  sq += __shfl_xor(sq, 1);
      sm += __shfl_xor(sm, 2);  sq += __shfl_xor(sq, 2);
      sm += __shfl_xor(sm, 4);  sq += __shfl_xor(sq, 4);
      sm += __shfl_xor(sm, 8);  sq += __shfl_xor(sq, 8);
      float mean = sm * (1.f / 128.f);
      float rstd = rsq_f(sq * (1.f / 128.f) - mean * mean + 1e-5f);
      f32x2 sc = (f32x2){rstd, rstd};
      f32x2 ofs = (f32x2){-mean * rstd, -mean * rstd};
      float o[8];
      #pragma unroll
      for (int p = 0; p < 4; p++) {
        f32x2 a = t2a[rr][p] * sc + ofs;
        a = a * g2[p] + be2[p];
        o[2 * p]     = silu_f(a[0]);
        o[2 * p + 1] = silu_f(a[1]);
      }
      uint4 st;
      st.x = cvt2bf(o[0], o[1]); st.y = cvt2bf(o[2], o[3]);
      st.z = cvt2bf(o[4], o[5]); st.w = cvt2bf(o[6], o[7]);
      *(uint4*)(s_t + m * AS_STRIDE + c0) = st;
    }
  }
  __syncthreads();

  f32x4 acc2[4][2];
  #pragma unroll
  for (int rt = 0; rt < 4; rt++)
    #pragma unroll
    for (int ct = 0; ct < 2; ct++)
      acc2[rt][ct] = (f32x4){0.f, 0.f, 0.f, 0.f};

  #pragma unroll
  for (int kk = 0; kk < 4; kk++) {               // K=128
    const int kl = kk * 32 + quad * 8;
    bf16x8 af[4];
    #pragma unroll
    for (int rt = 0; rt < 4; rt++)
      af[rt] = *(const bf16x8*)(s_t + (rt * 16 + l16) * AS_STRIDE + kl);
    #pragma unroll
    for (int ct = 0; ct < 2; ct++) {
      bf16x8 bfv = *(const bf16x8*)(W2T + (size_t)(c0w + ct * 16 + l16) * 128 + kl);
      #pragma unroll
      for (int rt = 0; rt < 4; rt++)
        acc2[rt][ct] = __builtin_amdgcn_mfma_f32_16x16x32_bf16(af[rt], bfv, acc2[rt][ct], 0, 0, 0);
    }
  }

  { // direct-from-register segmented flush: acc2 row rt*16+quad*4+r holds
    // sorted edge quad*16 + rt*4 + r -> thread owns 16 CONTIGUOUS sorted edges.
    // b2 dropped here; node adds cnt[dst]*b2 (verified r7).
    int dv[16];
    #pragma unroll
    for (int j = 0; j < 16; j++) dv[j] = s_dst[quad * 16 + j];

    #pragma unroll
    for (int ct = 0; ct < 2; ct++) {
      const int n = c0w + ct * 16 + l16;
      float* ap = aggr + n;
      int cur = dv[0];
      float run = 0.f;
      #pragma unroll
      for (int j = 0; j < 16; j++) {
        if (dv[j] != cur) {
          atomicAdd(ap + (size_t)cur * 128, run);
          run = 0.f; cur = dv[j];
        }
        run += acc2[j >> 2][ct][j & 3];
      }
      atomicAdd(ap + (size_t)cur * 128, run);
    }
  }
}

// ------ node MLP + residual + outer LN + fused next hd/hs OR fused decoder ---
__global__ __launch_bounds__(256, 4)
void node_mlp_kernel(u16* __restrict__ hbf, float* __restrict__ aggr,
                     const int* __restrict__ cnt, const float* __restrict__ eb2,
                     const u16* __restrict__ W1T, const float* __restrict__ b1,
                     const float* __restrict__ g, const float* __restrict__ be,
                     const u16* __restrict__ W2T, const float* __restrict__ b2,
                     const float* __restrict__ lng, const float* __restrict__ lnb,
                     const u16* __restrict__ W1Tn, const float* __restrict__ b1n,
                     u16* __restrict__ hd_all, u16* __restrict__ hs_all,
                     const float* __restrict__ x,
                     const u16* __restrict__ dW1T, const float* __restrict__ db1,
                     const u16* __restrict__ dW2T, const float* __restrict__ db2,
                     const u16* __restrict__ dW3T, const float* __restrict__ db3,
                     float* __restrict__ out,
                     int Nn) {
  __shared__ __align__(16) u16 As[128 * AS_STRIDE];  // 34,816 B
  u16* t_su = As;                    // [64][136]
  u16* u_su = As + 64 * AS_STRIDE;   // [64][136]

  const int tid = threadIdx.x;
  const int m0 = blockIdx.x * 64;
  const int w = tid >> 6, lane = tid & 63, quad = lane >> 4, l16 = lane & 15;
  const int c0w = w * 32;

  { // stage h (bf16 copy) + aggr (+cnt*b2e, f32 -> bf16), then zero aggr
    int r = tid >> 4, c8 = (tid & 15) * 8;
    const float4 z4 = {0.f, 0.f, 0.f, 0.f};
    const float4 e0 = *(const float4*)(eb2 + c8);
    const float4 e1 = *(const float4*)(eb2 + c8 + 4);
    #pragma unroll
    for (int rp = 0; rp < 4; rp++) {
      int m = rp * 16 + r;
      int node = m0 + m; if (node >= Nn) node = Nn - 1;
      *(uint4*)(As + m * AS_STRIDE + c8) = *(const uint4*)(hbf + (size_t)node * 128 + c8);
      float* ap = aggr + (size_t)node * 128 + c8;
      float cf = (float)cnt[node];   // aggr_true = aggr + cnt[dst]*b2 (b2 dropped in edge)
      float4 f0 = *(const float4*)ap;
      float4 f1 = *(const float4*)(ap + 4);
      f0.x += cf * e0.x; f0.y += cf * e0.y; f0.z += cf * e0.z; f0.w += cf * e0.w;
      f1.x += cf * e1.x; f1.y += cf * e1.y; f1.z += cf * e1.z; f1.w += cf * e1.w;
      uint4 pk;
      pk.x = cvt2bf(f0.x, f0.y); pk.y = cvt2bf(f0.z, f0.w);
      pk.z = cvt2bf(f1.x, f1.y); pk.w = cvt2bf(f1.z, f1.w);
      *(uint4*)(As + (64 + m) * AS_STRIDE + c8) = pk;
      *(float4*)ap = z4;
      *(float4*)(ap + 4) = z4;
    }
  }
  __syncthreads();

  f32x4 acc[4][2];
  #pragma unroll
  for (int rt = 0; rt < 4; rt++)
    #pragma unroll
    for (int ct = 0; ct < 2; ct++)
      acc[rt][ct] = (f32x4){0.f, 0.f, 0.f, 0.f};

  #pragma unroll
  for (int kk = 0; kk < 8; kk++) {
    const u16* Ab = As + (kk < 4 ? 0 : 64 * AS_STRIDE);
    const int kl = (kk & 3) * 32 + quad * 8;
    bf16x8 af[4];
    #pragma unroll
    for (int rt = 0; rt < 4; rt++)
      af[rt] = *(const bf16x8*)(Ab + (rt * 16 + l16) * AS_STRIDE + kl);
    const int kg = kk * 32 + quad * 8;
    #pragma unroll
    for (int ct = 0; ct < 2; ct++) {
      bf16x8 bfv = *(const bf16x8*)(W1T + (size_t)(c0w + ct * 16 + l16) * 256 + kg);
      #pragma unroll
      for (int rt = 0; rt < 4; rt++)
        acc[rt][ct] = __builtin_amdgcn_mfma_f32_16x16x32_bf16(af[rt], bfv, acc[rt][ct], 0, 0, 0);
    }
  }

  float b1v[2];
  #pragma unroll
  for (int ct = 0; ct < 2; ct++) b1v[ct] = b1[c0w + ct * 16 + l16];
  __syncthreads();

  #pragma unroll
  for (int rt = 0; rt < 4; rt++)
    #pragma unroll
    for (int ct = 0; ct < 2; ct++) {
      int n = c0w + ct * 16 + l16;
      #pragma unroll
      for (int r = 0; r < 4; r++)
        t_su[(rt * 16 + quad * 4 + r) * AS_STRIDE + n] = f2bf1(acc[rt][ct][r] + b1v[ct]);
    }
  __syncthreads();

  { // inner LN + SiLU: read t_su, write u_su
    int row = tid >> 2, sub = tid & 3;
    float s = 0.f, sq = 0.f, vals[32];
    #pragma unroll
    for (int i = 0; i < 32; i++) {
      float v = bf2f(t_su[row * AS_STRIDE + sub + i * 4]);
      vals[i] = v; s += v; sq += v * v;
    }
    s += __shfl_xor(s, 1); sq += __shfl_xor(sq, 1);
    s += __shfl_xor(s, 2); sq += __shfl_xor(sq, 2);
    float mean = s * (1.f / 128.f);
    float rstd = rsq_f(sq * (1.f / 128.f) - mean * mean + 1e-5f);
    #pragma unroll
    for (int i = 0; i < 32; i++) {
      int c = sub + i * 4;
      float a = (vals[i] - mean) * rstd * g[c] + be[c];
      u_su[row * AS_STRIDE + c] = f2bf1(silu_f(a));
    }
  }
  __syncthreads();

  f32x4 acc2[4][2];
  #pragma unroll
  for (int rt = 0; rt < 4; rt++)
    #pragma unroll
    for (int ct = 0; ct < 2; ct++)
      acc2[rt][ct] = (f32x4){0.f, 0.f, 0.f, 0.f};

  #pragma unroll
  for (int kk = 0; kk < 4; kk++) {
    const int kl = kk * 32 + quad * 8;
    bf16x8 af[4];
    #pragma unroll
    for (int rt = 0; rt < 4; rt++)
      af[rt] = *(const bf16x8*)(u_su + (rt * 16 + l16) * AS_STRIDE + kl);
    #pragma unroll
    for (int ct = 0; ct < 2; ct++) {
      bf16x8 bfv = *(const bf16x8*)(W2T + (size_t)(c0w + ct * 16 + l16) * 128 + kl);
      #pragma unroll
      for (int rt = 0; rt < 4; rt++)
        acc2[rt][ct] = __builtin_amdgcn_mfma_f32_16x16x32_bf16(af[rt], bfv, acc2[rt][ct], 0, 0, 0);
    }
  }
  __syncthreads();

  #pragma unroll
  for (int ct = 0; ct < 2; ct++) {
    int n = c0w + ct * 16 + l16;
    float b2v = b2[n];
    #pragma unroll
    for (int rt = 0; rt < 4; rt++)
      #pragma unroll
      for (int r = 0; r < 4; r++) {
        int m = rt * 16 + quad * 4 + r;
        int node = m0 + m; if (node >= Nn) node = Nn - 1;
        t_su[m * AS_STRIDE + n] =
            f2bf1(acc2[rt][ct][r] + b2v + bf2f(hbf[(size_t)node * 128 + n]));
      }
  }
  __syncthreads();

  { // outer LN -> hbf and back into t_su (A-layout h)
    int row = tid >> 2, sub = tid & 3;
    int node = m0 + row;
    float s = 0.f, sq = 0.f, vals[32];
    #pragma unroll
    for (int i = 0; i < 32; i++) {
      float v = bf2f(t_su[row * AS_STRIDE + sub + i * 4]);
      vals[i] = v; s += v; sq += v * v;
    }
    s += __shfl_xor(s, 1); sq += __shfl_xor(sq, 1);
    s += __shfl_xor(s, 2); sq += __shfl_xor(sq, 2);
    float mean = s * (1.f / 128.f);
    float rstd = rsq_f(sq * (1.f / 128.f) - mean * mean + 1e-5f);
    #pragma unroll
    for (int i = 0; i < 32; i++) {
      int c = sub + i * 4;
      float v = (vals[i] - mean) * rstd * lng[c] + lnb[c];
      u16 hb = f2bf1(v);
      t_su[row * AS_STRIDE + c] = hb;
      if (node < Nn) hbf[(size_t)node * 128 + c] = hb;
    }
  }

  if (W1Tn != nullptr) { // fused next-layer hd = h@W1d + b1, hs = h@W1s
    __syncthreads();
    f32x4 ah[4][2];
    #pragma unroll
    for (int rt = 0; rt < 4; rt++)
      #pragma unroll
      for (int ct = 0; ct < 2; ct++)
        ah[rt][ct] = (f32x4){0.f, 0.f, 0.f, 0.f};
    #pragma unroll
    for (int kk = 0; kk < 4; kk++) {
      const int kl = kk * 32 + quad * 8;
      bf16x8 af[4];
      #pragma unroll
      for (int rt = 0; rt < 4; rt++)
        af[rt] = *(const bf16x8*)(t_su + (rt * 16 + l16) * AS_STRIDE + kl);
      #pragma unroll
      for (int ct = 0; ct < 2; ct++) {
        bf16x8 bd = *(const bf16x8*)(W1Tn + (size_t)(c0w + ct * 16 + l16) * 256 + kl);
        #pragma unroll
        for (int rt = 0; rt < 4; rt++)
          ah[rt][ct] = __builtin_amdgcn_mfma_f32_16x16x32_bf16(af[rt], bd, ah[rt][ct], 0, 0, 0);
      }
    }
    #pragma unroll
    for (int ct = 0; ct < 2; ct++) {
      int n = c0w + ct * 16 + l16;
      float bv = b1n[n];
      #pragma unroll
      for (int rt = 0; rt < 4; rt++)
        #pragma unroll
        for (int r = 0; r < 4; r++) {
          int node = m0 + rt * 16 + quad * 4 + r;
          if (node < Nn) hd_all[(size_t)node * 128 + n] = f2bf1(ah[rt][ct][r] + bv);
        }
    }
    #pragma unroll
    for (int rt = 0; rt < 4; rt++)
      #pragma unroll
      for (int ct = 0; ct < 2; ct++)
        ah[rt][ct] = (f32x4){0.f, 0.f, 0.f, 0.f};
    #pragma unroll
    for (int kk = 0; kk < 4; kk++) {
      const int kl = kk * 32 + quad * 8;
      bf16x8 af[4];
      #pragma unroll
      for (int rt = 0; rt < 4; rt++)
        af[rt] = *(const bf16x8*)(t_su + (rt * 16 + l16) * AS_STRIDE + kl);
      #pragma unroll
      for (int ct = 0; ct < 2; ct++) {
        bf16x8 bs = *(const bf16x8*)(W1Tn + (size_t)(c0w + ct * 16 + l16) * 256 + 128 + kl);
        #pragma unroll
        for (int rt = 0; rt < 4; rt++)
          ah[rt][ct] = __builtin_amdgcn_mfma_f32_16x16x32_bf16(af[rt], bs, ah[rt][ct], 0, 0, 0);
      }
    }
    #pragma unroll
    for (int ct = 0; ct < 2; ct++) {
      int n = c0w + ct * 16 + l16;
      #pragma unroll
      for (int rt = 0; rt < 4; rt++)
        #pragma unroll
        for (int r = 0; r < 4; r++) {
          int node = m0 + rt * 16 + quad * 4 + r;
          if (node < Nn) hs_all[(size_t)node * 128 + n] = f2bf1(ah[rt][ct][r]);
        }
    }
  }

  if (dW1T != nullptr) { // fused decoder (layer 2): h in t_su (A-layout)
    __syncthreads();
    f32x4 da[4][2];
    #pragma unroll
    for (int rt = 0; rt < 4; rt++)
      #pragma unroll
      for (int ct = 0; ct < 2; ct++)
        da[rt][ct] = (f32x4){0.f, 0.f, 0.f, 0.f};
    #pragma unroll
    for (int kk = 0; kk < 4; kk++) {
      const int kl = kk * 32 + quad * 8;
      bf16x8 af[4];
      #pragma unroll
      for (int rt = 0; rt < 4; rt++)
        af[rt] = *(const bf16x8*)(t_su + (rt * 16 + l16) * AS_STRIDE + kl);
      #pragma unroll
      for (int ct = 0; ct < 2; ct++) {
        bf16x8 bfv = *(const bf16x8*)(dW1T + (size_t)(c0w + ct * 16 + l16) * 128 + kl);
        #pragma unroll
        for (int rt = 0; rt < 4; rt++)
          da[rt][ct] = __builtin_amdgcn_mfma_f32_16x16x32_bf16(af[rt], bfv, da[rt][ct], 0, 0, 0);
      }
    }
    __syncthreads();
    #pragma unroll
    for (int ct = 0; ct < 2; ct++) {
      int n = c0w + ct * 16 + l16;
      float bv = db1[n];
      #pragma unroll
      for (int rt = 0; rt < 4; rt++)
        #pragma unroll
        for (int r = 0; r < 4; r++)
          u_su[(rt * 16 + quad * 4 + r) * AS_STRIDE + n] = f2bf1(silu_f(da[rt][ct][r] + bv));
    }
    __syncthreads();
    { // dec L2: 64 cols, wave covers 16; u2 overwrites t_su region
      const int c0b = w * 16;
      f32x4 a2[4];
      #pragma unroll
      for (int rt = 0; rt < 4; rt++) a2[rt] = (f32x4){0.f, 0.f, 0.f, 0.f};
      #pragma unroll
      for (int kk = 0; kk < 4; kk++) {
        const int kl = kk * 32 + quad * 8;
        bf16x8 af[4];
        #pragma unroll
        for (int rt = 0; rt < 4; rt++)
          af[rt] = *(const bf16x8*)(u_su + (rt * 16 + l16) * AS_STRIDE + kl);
        bf16x8 bfv = *(const bf16x8*)(dW2T + (size_t)(c0b + l16) * 128 + kl);
        #pragma unroll
        for (int rt = 0; rt < 4; rt++)
          a2[rt] = __builtin_amdgcn_mfma_f32_16x16x32_bf16(af[rt], bfv, a2[rt], 0, 0, 0);
      }
      float bv = db2[c0b + l16];
      #pragma unroll
      for (int rt = 0; rt < 4; rt++)
        #pragma unroll
        for (int r = 0; r < 4; r++)
          t_su[(rt * 16 + quad * 4 + r) * 72 + c0b + l16] = f2bf1(silu_f(a2[rt][r] + bv));
    }
    __syncthreads();
    if (w == 0) { // dec L3: 6 cols (padded 16), K=64
      f32x4 a3[4];
      #pragma unroll
      for (int rt = 0; rt < 4; rt++) a3[rt] = (f32x4){0.f, 0.f, 0.f, 0.f};
      #pragma unroll
      for (int kk = 0; kk < 2; kk++) {
        const int kl = kk * 32 + quad * 8;
        bf16x8 af[4];
        #pragma unroll
        for (int rt = 0; rt < 4; rt++)
          af[rt] = *(const bf16x8*)(t_su + (rt * 16 + l16) * 72 + kl);
        bf16x8 bfv = *(const bf16x8*)(dW3T + l16 * 64 + kl);
        #pragma unroll
        for (int rt = 0; rt < 4; rt++)
          a3[rt] = __builtin_amdgcn_mfma_f32_16x16x32_bf16(af[rt], bfv, a3[rt], 0, 0, 0);
      }
      if (l16 < 6) {
        float bv = db3[l16];
        #pragma unroll
        for (int rt = 0; rt < 4; rt++)
          #pragma unroll
          for (int r = 0; r < 4; r++) {
            int node = m0 + rt * 16 + quad * 4 + r;
            if (node < Nn)
              out[(size_t)node * 6 + l16] = a3[rt][r] + bv + x[node * 7 + l16];
          }
      }
    }
  }
}

// ---------------- host launcher ----------------------------------------------
extern "C" void kernel_launch(void* const* d_in, const int* in_sizes, int n_in,
                              void* d_out, int out_size, void* d_ws, size_t ws_size,
                              hipStream_t stream) {
  const float* x      = (const float*)d_in[0];
  const float* pos    = (const float*)d_in[1];
  const int*   eidx   = (const int*)d_in[2];
  const float* enc_w1 = (const float*)d_in[3];
  const float* enc_b1 = (const float*)d_in[4];
  const float* enc_g  = (const float*)d_in[5];
  const float* enc_be = (const float*)d_in[6];
  const float* enc_w2 = (const float*)d_in[7];
  const float* enc_b2 = (const float*)d_in[8];
  const float* e_w1   = (const float*)d_in[9];
  const float* e_b1   = (const float*)d_in[10];
  const float* e_g    = (const float*)d_in[11];
  const float* e_be   = (const float*)d_in[12];
  const float* e_w2   = (const float*)d_in[13];
  const float* e_b2   = (const float*)d_in[14];
  const float* n_w1   = (const float*)d_in[15];
  const float* n_b1   = (const float*)d_in[16];
  const float* n_g    = (const float*)d_in[17];
  const float* n_be   = (const float*)d_in[18];
  const float* n_w2   = (const float*)d_in[19];
  const float* n_b2   = (const float*)d_in[20];
  const float* ln_g   = (const float*)d_in[21];
  const float* ln_b   = (const float*)d_in[22];
  const float* dec_w1 = (const float*)d_in[23];
  const float* dec_b1 = (const float*)d_in[24];
  const float* dec_w2 = (const float*)d_in[25];
  const float* dec_b2 = (const float*)d_in[26];
  const float* dec_w3 = (const float*)d_in[27];
  const float* dec_b3 = (const float*)d_in[28];

  const int N = in_sizes[0] / 7;          // 50000
  const int E = in_sizes[2] / 2;          // 1600000

  char* ws = (char*)d_ws;
  size_t off = 0;
  u16*   hbf    = (u16*)(ws + off);   off += (size_t)N * 128 * 2;
  u16*   hd_all = (u16*)(ws + off);   off += (size_t)N * 128 * 2;
  u16*   hs_all = (u16*)(ws + off);   off += (size_t)N * 128 * 2;
  float* aggr   = (float*)(ws + off); off += (size_t)N * 128 * 4;
  u16* eW1T = (u16*)(ws + off); off += 3 * 128 * 256 * 2;
  u16* eW2T = (u16*)(ws + off); off += 3 * 128 * 128 * 2;
  u16* nW1T = (u16*)(ws + off); off += 3 * 128 * 256 * 2;
  u16* nW2T = (u16*)(ws + off); off += 3 * 128 * 128 * 2;
  u16* encW1T = (u16*)(ws + off); off += 128 * 32 * 2;
  u16* encW2T = (u16*)(ws + off); off += 128 * 128 * 2;
  u16* decW1T = (u16*)(ws + off); off += 128 * 128 * 2;
  u16* decW2T = (u16*)(ws + off); off += 64 * 128 * 2;
  u16* decW3T = (u16*)(ws + off); off += 16 * 64 * 2;
  int* cnt    = (int*)(ws + off); off += (size_t)N * 4;
  int* cursor = (int*)(ws + off); off += (size_t)N * 4;
  int2* sedge = (int2*)(ws + off); off += (size_t)E * 8;

  // sort edges by dst once (reused across all 3 layers); cnt preserved for node
  hipMemsetAsync(cnt, 0, (size_t)N * 4, stream);
  edge_hist<<<(E + 255) / 256, 256, 0, stream>>>(eidx + E, E, cnt);
  scan_kernel<<<1, 1024, 0, stream>>>(cnt, cursor, N);
  edge_scatter<<<(E + 255) / 256, 256, 0, stream>>>(eidx, eidx + E, E, cursor, sedge);

  prep_weights<<<1152, 256, 0, stream>>>(e_w1, e_w2, n_w1, n_w2, eW1T, eW2T, nW1T, nW2T);
  prep_weights2<<<180, 256, 0, stream>>>(enc_w1, enc_w2, dec_w1, dec_w2, dec_w3,
                                         encW1T, encW2T, decW1T, decW2T, decW3T);

  // zero aggr ONCE; node_mlp re-zeroes its rows for the next layer after reading
  hipMemsetAsync(aggr, 0, (size_t)N * 128 * 4, stream);

  const int nblk = (N + 63) / 64;
  encoder_mfma<<<nblk, 256, 0, stream>>>(x, encW1T, enc_b1, enc_g, enc_be, encW2T, enc_b2,
                                         eW1T, e_b1, hbf, hd_all, hs_all, N);

  for (int l = 0; l < 3; l++) {
    edge_mlp_kernel<<<E / 64, 256, 0, stream>>>(
        sedge, pos, hd_all, hs_all,
        e_w1 + (size_t)l * 33408 + 256 * 128,   // W1c rows as f32 [5][128]
        e_g + l * 128, e_be + l * 128,
        eW2T + (size_t)l * 128 * 128, aggr);
    const u16* W1Tn = (l < 2) ? (eW1T + (size_t)(l + 1) * 128 * 256) : (const u16*)nullptr;
    const bool last = (l == 2);
    node_mlp_kernel<<<nblk, 256, 0, stream>>>(
        hbf, aggr, cnt, e_b2 + l * 128,
        nW1T + (size_t)l * 128 * 256, n_b1 + l * 128, n_g + l * 128, n_be + l * 128,
        nW2T + (size_t)l * 128 * 128, n_b2 + l * 128,
        ln_g + l * 128, ln_b + l * 128,
        W1Tn, e_b1 + ((l + 1) % 3) * 128, hd_all, hs_all,
        x,
        last ? decW1T : (const u16*)nullptr, dec_b1,
        last ? decW2T : (const u16*)nullptr, dec_b2,
        last ? decW3T : (const u16*)nullptr, dec_b3,
        (float*)d_out, N);
  }
}

// Round 9
// 1146.713 us; speedup vs baseline: 1.6888x; 1.0164x over previous
//
#include <hip/hip_runtime.h>

typedef unsigned short u16;
typedef unsigned int u32;
typedef __bf16 bf16x8 __attribute__((ext_vector_type(8)));
typedef float f32x4 __attribute__((ext_vector_type(4)));
typedef float f32x2 __attribute__((ext_vector_type(2)));

#define AS_STRIDE 136   // bf16 elems per LDS A-row (128 + 8 pad; 16B-aligned rows)

__device__ __forceinline__ u16 f2bf1(float f) {
  union { __bf16 h; u16 u; } c; c.h = (__bf16)f; return c.u;
}
__device__ __forceinline__ u32 cvt2bf(float a, float b) {
  union { __bf16 h[2]; u32 u; } c; c.h[0] = (__bf16)a; c.h[1] = (__bf16)b; return c.u;
}
__device__ __forceinline__ float bf2f(u16 u) {
  union { u32 u; float f; } v; v.u = ((u32)u) << 16; return v.f;
}
// silu via v_rcp_f32 (2 ops) instead of IEEE f32 divide (~10-op sequence)
__device__ __forceinline__ float silu_f(float a) {
  return a * __builtin_amdgcn_rcpf(1.f + __expf(-a));
}
__device__ __forceinline__ float rsq_f(float x) {
  return __builtin_amdgcn_rsqf(x);
}
__device__ __forceinline__ f32x2 unpk2(u32 p) {
  union { u32 u; float f; } a, b;
  a.u = p << 16; b.u = p & 0xffff0000u;
  return (f32x2){a.f, b.f};
}
// involution mapping LDS row -> sorted-edge index: swaps the rt and quad fields
// P(rt*16 + quad*4 + r) = quad*16 + rt*4 + r  (P(P(i)) == i)
__device__ __forceinline__ int permP(int i) {
  return ((i >> 2) & 3) * 16 + ((i >> 4) & 3) * 4 + (i & 3);
}

// ---------------- edge sort by dst (counting sort, once per call) ------------
__global__ void edge_hist(const int* __restrict__ edst, int E, int* __restrict__ cnt) {
  int i = blockIdx.x * blockDim.x + threadIdx.x;
  if (i < E) atomicAdd(&cnt[edst[i]], 1);
}

__global__ __launch_bounds__(1024)
void scan_kernel(const int* __restrict__ cnt, int* __restrict__ cursor, int Nn) {
  __shared__ int part[1024];
  int t = threadIdx.x;
  int per = (Nn + 1023) / 1024;
  int b = t * per;
  int s = 0;
  for (int i = 0; i < per; i++) { int idx = b + i; if (idx < Nn) s += cnt[idx]; }
  part[t] = s;
  __syncthreads();
  for (int d = 1; d < 1024; d <<= 1) {
    int v = (t >= d) ? part[t - d] : 0;
    __syncthreads();
    part[t] += v;
    __syncthreads();
  }
  int excl = (t == 0) ? 0 : part[t - 1];
  for (int i = 0; i < per; i++) {
    int idx = b + i;
    if (idx < Nn) { cursor[idx] = excl; excl += cnt[idx]; }
  }
}

__global__ void edge_scatter(const int* __restrict__ esrc, const int* __restrict__ edst,
                             int E, int* __restrict__ cursor,
                             int* __restrict__ ssrc, int* __restrict__ sdst) {
  int i = blockIdx.x * blockDim.x + threadIdx.x;
  if (i < E) {
    int d = edst[i];
    int p = atomicAdd(&cursor[d], 1);
    ssrc[p] = esrc[i];
    sdst[p] = d;
  }
}

// ---------------- weight prep: transpose + bf16-cast -------------------------
__global__ void prep_weights(const float* __restrict__ e_w1, const float* __restrict__ e_w2,
                             const float* __restrict__ n_w1, const float* __restrict__ n_w2,
                             u16* __restrict__ eW1T, u16* __restrict__ eW2T,
                             u16* __restrict__ nW1T, u16* __restrict__ nW2T) {
  int i = blockIdx.x * blockDim.x + threadIdx.x;
  const int s1 = 3 * 128 * 256;
  const int s2 = 3 * 128 * 128;
  if (i < s1) {
    int l = i / 32768, r = i % 32768, n = r >> 8, k = r & 255;
    eW1T[i] = f2bf1(e_w1[l * 33408 + k * 128 + n]);
  } else if (i < s1 + s2) {
    int j = i - s1; int l = j / 16384, r = j % 16384, n = r >> 7, k = r & 127;
    eW2T[j] = f2bf1(e_w2[l * 16384 + k * 128 + n]);
  } else if (i < s1 + s2 + s1) {
    int j = i - s1 - s2; int l = j / 32768, r = j % 32768, n = r >> 8, k = r & 255;
    nW1T[j] = f2bf1(n_w1[l * 32768 + k * 128 + n]);
  } else if (i < 2 * s1 + 2 * s2) {
    int j = i - 2 * s1 - s2; int l = j / 16384, r = j % 16384, n = r >> 7, k = r & 127;
    nW2T[j] = f2bf1(n_w2[l * 16384 + k * 128 + n]);
  }
}

// enc/dec weights (edge-attr weight consumed as f32 directly from e_w1)
__global__ void prep_weights2(const float* __restrict__ enc_w1, const float* __restrict__ enc_w2,
                              const float* __restrict__ dec_w1, const float* __restrict__ dec_w2,
                              const float* __restrict__ dec_w3,
                              u16* __restrict__ encW1T, u16* __restrict__ encW2T,
                              u16* __restrict__ decW1T, u16* __restrict__ decW2T,
                              u16* __restrict__ decW3T) {
  int i = blockIdx.x * blockDim.x + threadIdx.x;
  if (i < 4096) {
    int n = i >> 5, k = i & 31;
    encW1T[i] = (k < 7) ? f2bf1(enc_w1[k * 128 + n]) : (u16)0;
  } else if (i < 20480) {
    int j = i - 4096; int n = j >> 7, k = j & 127;
    encW2T[j] = f2bf1(enc_w2[k * 128 + n]);
  } else if (i < 36864) {
    int j = i - 20480; int n = j >> 7, k = j & 127;
    decW1T[j] = f2bf1(dec_w1[k * 128 + n]);
  } else if (i < 45056) {
    int j = i - 36864; int n = j >> 7, k = j & 127;
    decW2T[j] = f2bf1(dec_w2[k * 64 + n]);
  } else if (i < 46080) {
    int j = i - 45056; int n = j >> 6, k = j & 63;
    decW3T[j] = (n < 6) ? f2bf1(dec_w3[k * 6 + n]) : (u16)0;
  }
}

// ---------------- encoder (MFMA) + fused hd/hs for layer 0 -------------------
__global__ __launch_bounds__(256, 4)
void encoder_mfma(const float* __restrict__ x,
                  const u16* __restrict__ W1T,   // [128][32]
                  const float* __restrict__ b1,
                  const float* __restrict__ g, const float* __restrict__ be,
                  const u16* __restrict__ W2T,   // [128][128]
                  const float* __restrict__ b2,
                  const u16* __restrict__ eW1T0, // [128][256] layer-0 edge W1
                  const float* __restrict__ eb10,
                  u16* __restrict__ hbf, u16* __restrict__ hd_all,
                  u16* __restrict__ hs_all, int Nn) {
  __shared__ __align__(16) u16 As[64 * 40];
  __shared__ __align__(16) u16 ts[64 * AS_STRIDE];
  const int tid = threadIdx.x;
  const int m0 = blockIdx.x * 64;
  const int w = tid >> 6, lane = tid & 63, quad = lane >> 4, l16 = lane & 15;
  const int c0w = w * 32;

  if (tid < 64) {
    int node = m0 + tid; if (node >= Nn) node = Nn - 1;
    union { u16 us[32]; uint4 v[4]; } pk;
    #pragma unroll
    for (int k = 0; k < 32; k++) pk.us[k] = 0;
    #pragma unroll
    for (int k = 0; k < 7; k++) pk.us[k] = f2bf1(x[node * 7 + k]);
    #pragma unroll
    for (int k = 0; k < 4; k++) *(uint4*)(As + tid * 40 + k * 8) = pk.v[k];
  }
  __syncthreads();

  f32x4 acc[4][2];
  #pragma unroll
  for (int rt = 0; rt < 4; rt++)
    #pragma unroll
    for (int ct = 0; ct < 2; ct++)
      acc[rt][ct] = (f32x4){0.f, 0.f, 0.f, 0.f};
  {
    const int kl = quad * 8;
    bf16x8 af[4];
    #pragma unroll
    for (int rt = 0; rt < 4; rt++)
      af[rt] = *(const bf16x8*)(As + (rt * 16 + l16) * 40 + kl);
    #pragma unroll
    for (int ct = 0; ct < 2; ct++) {
      bf16x8 bfv = *(const bf16x8*)(W1T + (c0w + ct * 16 + l16) * 32 + kl);
      #pragma unroll
      for (int rt = 0; rt < 4; rt++)
        acc[rt][ct] = __builtin_amdgcn_mfma_f32_16x16x32_bf16(af[rt], bfv, acc[rt][ct], 0, 0, 0);
    }
  }
  #pragma unroll
  for (int ct = 0; ct < 2; ct++) {
    int n = c0w + ct * 16 + l16;
    float b1v = b1[n];
    #pragma unroll
    for (int rt = 0; rt < 4; rt++)
      #pragma unroll
      for (int r = 0; r < 4; r++)
        ts[(rt * 16 + quad * 4 + r) * AS_STRIDE + n] = f2bf1(acc[rt][ct][r] + b1v);
  }
  __syncthreads();

  { // LN + SiLU in place (bf16)
    int row = tid >> 2, sub = tid & 3;
    float s = 0.f, sq = 0.f, vals[32];
    #pragma unroll
    for (int i = 0; i < 32; i++) {
      float v = bf2f(ts[row * AS_STRIDE + sub + i * 4]);
      vals[i] = v; s += v; sq += v * v;
    }
    s += __shfl_xor(s, 1); sq += __shfl_xor(sq, 1);
    s += __shfl_xor(s, 2); sq += __shfl_xor(sq, 2);
    float mean = s * (1.f / 128.f);
    float rstd = rsq_f(sq * (1.f / 128.f) - mean * mean + 1e-5f);
    #pragma unroll
    for (int i = 0; i < 32; i++) {
      int c = sub + i * 4;
      float a = (vals[i] - mean) * rstd * g[c] + be[c];
      ts[row * AS_STRIDE + c] = f2bf1(silu_f(a));
    }
  }
  __syncthreads();

  f32x4 acc2[4][2];
  #pragma unroll
  for (int rt = 0; rt < 4; rt++)
    #pragma unroll
    for (int ct = 0; ct < 2; ct++)
      acc2[rt][ct] = (f32x4){0.f, 0.f, 0.f, 0.f};
  #pragma unroll
  for (int kk = 0; kk < 4; kk++) {
    const int kl = kk * 32 + quad * 8;
    bf16x8 af[4];
    #pragma unroll
    for (int rt = 0; rt < 4; rt++)
      af[rt] = *(const bf16x8*)(ts + (rt * 16 + l16) * AS_STRIDE + kl);
    #pragma unroll
    for (int ct = 0; ct < 2; ct++) {
      bf16x8 bfv = *(const bf16x8*)(W2T + (size_t)(c0w + ct * 16 + l16) * 128 + kl);
      #pragma unroll
      for (int rt = 0; rt < 4; rt++)
        acc2[rt][ct] = __builtin_amdgcn_mfma_f32_16x16x32_bf16(af[rt], bfv, acc2[rt][ct], 0, 0, 0);
    }
  }
  __syncthreads();   // ts reads done; rewrite with h
  #pragma unroll
  for (int ct = 0; ct < 2; ct++) {
    int n = c0w + ct * 16 + l16;
    float b2v = b2[n];
    #pragma unroll
    for (int rt = 0; rt < 4; rt++)
      #pragma unroll
      for (int r = 0; r < 4; r++) {
        int m = rt * 16 + quad * 4 + r;
        int node = m0 + m;
        u16 hb = f2bf1(acc2[rt][ct][r] + b2v);
        ts[m * AS_STRIDE + n] = hb;
        if (node < Nn) hbf[(size_t)node * 128 + n] = hb;
      }
  }
  __syncthreads();

  { // fused hd = h@W1d + b1, then hs = h@W1s (layer 0)
    f32x4 ah[4][2];
    #pragma unroll
    for (int rt = 0; rt < 4; rt++)
      #pragma unroll
      for (int ct = 0; ct < 2; ct++)
        ah[rt][ct] = (f32x4){0.f, 0.f, 0.f, 0.f};
    #pragma unroll
    for (int kk = 0; kk < 4; kk++) {
      const int kl = kk * 32 + quad * 8;
      bf16x8 af[4];
      #pragma unroll
      for (int rt = 0; rt < 4; rt++)
        af[rt] = *(const bf16x8*)(ts + (rt * 16 + l16) * AS_STRIDE + kl);
      #pragma unroll
      for (int ct = 0; ct < 2; ct++) {
        bf16x8 bd = *(const bf16x8*)(eW1T0 + (size_t)(c0w + ct * 16 + l16) * 256 + kl);
        #pragma unroll
        for (int rt = 0; rt < 4; rt++)
          ah[rt][ct] = __builtin_amdgcn_mfma_f32_16x16x32_bf16(af[rt], bd, ah[rt][ct], 0, 0, 0);
      }
    }
    #pragma unroll
    for (int ct = 0; ct < 2; ct++) {
      int n = c0w + ct * 16 + l16;
      float b1v = eb10[n];
      #pragma unroll
      for (int rt = 0; rt < 4; rt++)
        #pragma unroll
        for (int r = 0; r < 4; r++) {
          int node = m0 + rt * 16 + quad * 4 + r;
          if (node < Nn) hd_all[(size_t)node * 128 + n] = f2bf1(ah[rt][ct][r] + b1v);
        }
    }
    #pragma unroll
    for (int rt = 0; rt < 4; rt++)
      #pragma unroll
      for (int ct = 0; ct < 2; ct++)
        ah[rt][ct] = (f32x4){0.f, 0.f, 0.f, 0.f};
    #pragma unroll
    for (int kk = 0; kk < 4; kk++) {
      const int kl = kk * 32 + quad * 8;
      bf16x8 af[4];
      #pragma unroll
      for (int rt = 0; rt < 4; rt++)
        af[rt] = *(const bf16x8*)(ts + (rt * 16 + l16) * AS_STRIDE + kl);
      #pragma unroll
      for (int ct = 0; ct < 2; ct++) {
        bf16x8 bs = *(const bf16x8*)(eW1T0 + (size_t)(c0w + ct * 16 + l16) * 256 + 128 + kl);
        #pragma unroll
        for (int rt = 0; rt < 4; rt++)
          ah[rt][ct] = __builtin_amdgcn_mfma_f32_16x16x32_bf16(af[rt], bs, ah[rt][ct], 0, 0, 0);
      }
    }
    #pragma unroll
    for (int ct = 0; ct < 2; ct++) {
      int n = c0w + ct * 16 + l16;
      #pragma unroll
      for (int rt = 0; rt < 4; rt++)
        #pragma unroll
        for (int r = 0; r < 4; r++) {
          int node = m0 + rt * 16 + quad * 4 + r;
          if (node < Nn) hs_all[(size_t)node * 128 + n] = f2bf1(ah[rt][ct][r]);
        }
    }
  }
}

// ---------------- edge MLP: rank-5 ea term in registers (r9 structure) -------
// r12 = r6 exact (verified 1133us total) with ONE change: 6 -> 7 blocks/CU
// (LDS 22272B x 7 = 155.9KB <= 160KB). Probing the concurrency/L2-churn knee
// between 6 (268MB hbm) and 8 (1.32GB, r3 blowup). Abort: WRITE>200MB.
__global__ __launch_bounds__(256, 7)
void edge_mlp_kernel(const int* __restrict__ ssrc, const int* __restrict__ sdst,
                     const float* __restrict__ pos,
                     const u16* __restrict__ hd_all, const u16* __restrict__ hs_all,
                     const float* __restrict__ w1cF, // [5][128] f32 (= e_w1 rows 256..260)
                     const float* __restrict__ g, const float* __restrict__ be,
                     const u16* __restrict__ W2T,   // [128][128] bf16
                     const float* __restrict__ b2,
                     float* __restrict__ aggr) {
  __shared__ int s_dst[64];                           // dst of SORTED edge e0+i
  __shared__ __align__(16) float s_ea[64 * 8];        // ea feats f32, row i = edge P(i)
  __shared__ __align__(16) float s_w1c[5 * 128];      // W1c f32
  __shared__ __align__(16) u16 s_t[64 * AS_STRIDE];   // u (row i = edge P(i))

  const int tid = threadIdx.x;
  // XCD swizzle: consecutive-dst chunks stay on one XCD
  const int bid = blockIdx.x;
  const int e0 = ((bid & 7) * (gridDim.x >> 3) + (bid >> 3)) * 64;
  const int w = tid >> 6, lane = tid & 63, quad = lane >> 4, l16 = lane & 15;
  const int c0w = w * 32;
  const int rg = tid >> 4, cg = tid & 15;
  const int c0 = cg * 8;

  // ---- prefetch ALL phase-A gathers at kernel top; fence pins issue order ----
  int pdst[4], psrc[4];
  #pragma unroll
  for (int rr = 0; rr < 4; rr++) {
    int j = permP(rg * 4 + rr);          // LDS row rg*4+rr holds edge e0+P(row)
    pdst[rr] = sdst[e0 + j];
    psrc[rr] = ssrc[e0 + j];
  }
  uint4 hd4[4], hs4[4];
  #pragma unroll
  for (int rr = 0; rr < 4; rr++) {
    hd4[rr] = *(const uint4*)(hd_all + (size_t)pdst[rr] * 128 + c0);
    hs4[rr] = *(const uint4*)(hs_all + (size_t)psrc[rr] * 128 + c0);
  }
  asm volatile("" ::: "memory");  // compiler fence: loads cannot sink below

  if (tid < 64) {
    int jp = permP(tid);
    int src = ssrc[e0 + jp], dst = sdst[e0 + jp];
    s_dst[tid] = sdst[e0 + tid];          // sorted order, for the atomic flush
    float dx = pos[dst * 3 + 0] - pos[src * 3 + 0];
    float dy = pos[dst * 3 + 1] - pos[src * 3 + 1];
    float dz = pos[dst * 3 + 2] - pos[src * 3 + 2];
    float dist = sqrtf(dx * dx + dy * dy + dz * dz) + 1e-8f;
    float inv = __builtin_amdgcn_rcpf(dist);
    s_ea[tid * 8 + 0] = dist;
    s_ea[tid * 8 + 1] = dx * inv;
    s_ea[tid * 8 + 2] = dy * inv;
    s_ea[tid * 8 + 3] = dz * inv;
    s_ea[tid * 8 + 4] = __builtin_amdgcn_rcpf(dist * dist + 1e-6f);
  }
  if (tid < 160) *(float4*)(s_w1c + tid * 4) = *(const float4*)(w1cF + tid * 4);
  __syncthreads();

  { // phase A: t = hd[dst] + hs[src] + ea@W1c (rank-5, f32); LN+SiLU -> u in s_t
    f32x2 t2a[4][4];
    #pragma unroll
    for (int rr = 0; rr < 4; rr++) {
      u32 hp[4] = {hd4[rr].x, hd4[rr].y, hd4[rr].z, hd4[rr].w};
      u32 sp[4] = {hs4[rr].x, hs4[rr].y, hs4[rr].z, hs4[rr].w};
      #pragma unroll
      for (int p = 0; p < 4; p++)
        t2a[rr][p] = unpk2(hp[p]) + unpk2(sp[p]);
    }
    #pragma unroll
    for (int k = 0; k < 5; k++) {
      f32x4 wa = *(const f32x4*)(s_w1c + k * 128 + c0);
      f32x4 wb = *(const f32x4*)(s_w1c + k * 128 + c0 + 4);
      f32x2 wk0 = (f32x2){wa[0], wa[1]}, wk1 = (f32x2){wa[2], wa[3]};
      f32x2 wk2 = (f32x2){wb[0], wb[1]}, wk3 = (f32x2){wb[2], wb[3]};
      #pragma unroll
      for (int rr = 0; rr < 4; rr++) {
        float e = s_ea[(rg * 4 + rr) * 8 + k];
        f32x2 ev = (f32x2){e, e};
        t2a[rr][0] += ev * wk0;
        t2a[rr][1] += ev * wk1;
        t2a[rr][2] += ev * wk2;
        t2a[rr][3] += ev * wk3;
      }
    }
    f32x2 g2[4], be2[4];
    {
      f32x4 ga = *(const f32x4*)(g + c0), gb = *(const f32x4*)(g + c0 + 4);
      f32x4 ba = *(const f32x4*)(be + c0), bb = *(const f32x4*)(be + c0 + 4);
      g2[0] = (f32x2){ga[0], ga[1]}; g2[1] = (f32x2){ga[2], ga[3]};
      g2[2] = (f32x2){gb[0], gb[1]}; g2[3] = (f32x2){gb[2], gb[3]};
      be2[0] = (f32x2){ba[0], ba[1]}; be2[1] = (f32x2){ba[2], ba[3]};
      be2[2] = (f32x2){bb[0], bb[1]}; be2[3] = (f32x2){bb[2], bb[3]};
    }
    #pragma unroll
    for (int rr = 0; rr < 4; rr++) {
      int m = rg * 4 + rr;
      f32x2 sm2 = (f32x2){0.f, 0.f}, sq2 = (f32x2){0.f, 0.f};
      #pragma unroll
      for (int p = 0; p < 4; p++) {
        sm2 += t2a[rr][p];
        sq2 += t2a[rr][p] * t2a[rr][p];
      }
      float sm = sm2[0] + sm2[1], sq = sq2[0] + sq2[1];
      sm += __shfl_xor(sm, 1);  sq += __shfl_xor(sq, 1);
      sm += __shfl_xor(sm, 2);  sq += __shfl_xor(sq, 2);
      sm += __shfl_xor(sm, 4);  sq += __shfl_xor(sq, 4);
      sm += __shfl_xor(sm, 8);  sq += __shfl_xor(sq, 8);
      float mean = sm * (1.f / 128.f);
      float rstd = rsq_f(sq * (1.f / 128.f) - mean * mean + 1e-5f);
      f32x2 sc = (f32x2){rstd, rstd};
      f32x2 ofs = (f32x2){-mean * rstd, -mean * rstd};
      float o[8];
      #pragma unroll
      for (int p = 0; p < 4; p++) {
        f32x2 a = t2a[rr][p] * sc + ofs;
        a = a * g2[p] + be2[p];
        o[2 * p]     = silu_f(a[0]);
        o[2 * p + 1] = silu_f(a[1]);
      }
      uint4 st;
      st.x = cvt2bf(o[0], o[1]); st.y = cvt2bf(o[2], o[3]);
      st.z = cvt2bf(o[4], o[5]); st.w = cvt2bf(o[6], o[7]);
      *(uint4*)(s_t + m * AS_STRIDE + c0) = st;
    }
  }
  __syncthreads();

  f32x4 acc2[4][2];
  #pragma unroll
  for (int rt = 0; rt < 4; rt++)
    #pragma unroll
    for (int ct = 0; ct < 2; ct++)
      acc2[rt][ct] = (f32x4){0.f, 0.f, 0.f, 0.f};

  #pragma unroll
  for (int kk = 0; kk < 4; kk++) {               // K=128
    const int kl = kk * 32 + quad * 8;
    bf16x8 af[4];
    #pragma unroll
    for (int rt = 0; rt < 4; rt++)
      af[rt] = *(const bf16x8*)(s_t + (rt * 16 + l16) * AS_STRIDE + kl);
    #pragma unroll
    for (int ct = 0; ct < 2; ct++) {
      bf16x8 bfv = *(const bf16x8*)(W2T + (size_t)(c0w + ct * 16 + l16) * 128 + kl);
      #pragma unroll
      for (int rt = 0; rt < 4; rt++)
        acc2[rt][ct] = __builtin_amdgcn_mfma_f32_16x16x32_bf16(af[rt], bfv, acc2[rt][ct], 0, 0, 0);
    }
  }

  { // direct-from-register segmented flush: acc2 row rt*16+quad*4+r holds
    // sorted edge quad*16 + rt*4 + r -> thread owns 16 CONTIGUOUS sorted edges
    int dv[16];
    #pragma unroll
    for (int j = 0; j < 16; j++) dv[j] = s_dst[quad * 16 + j];

    #pragma unroll
    for (int ct = 0; ct < 2; ct++) {
      const int n = c0w + ct * 16 + l16;
      const float b2v = b2[n];
      float* ap = aggr + n;
      int cur = dv[0];
      float run = 0.f;
      #pragma unroll
      for (int j = 0; j < 16; j++) {
        if (dv[j] != cur) {
          atomicAdd(ap + (size_t)cur * 128, run);
          run = 0.f; cur = dv[j];
        }
        run += acc2[j >> 2][ct][j & 3] + b2v;
      }
      atomicAdd(ap + (size_t)cur * 128, run);
    }
  }
}

// ------ node MLP + residual + outer LN + fused next hd/hs OR fused decoder ---
__global__ __launch_bounds__(256, 4)
void node_mlp_kernel(u16* __restrict__ hbf, float* __restrict__ aggr,
                     const u16* __restrict__ W1T, const float* __restrict__ b1,
                     const float* __restrict__ g, const float* __restrict__ be,
                     const u16* __restrict__ W2T, const float* __restrict__ b2,
                     const float* __restrict__ lng, const float* __restrict__ lnb,
                     const u16* __restrict__ W1Tn, const float* __restrict__ b1n,
                     u16* __restrict__ hd_all, u16* __restrict__ hs_all,
                     const float* __restrict__ x,
                     const u16* __restrict__ dW1T, const float* __restrict__ db1,
                     const u16* __restrict__ dW2T, const float* __restrict__ db2,
                     const u16* __restrict__ dW3T, const float* __restrict__ db3,
                     float* __restrict__ out,
                     int Nn) {
  __shared__ __align__(16) u16 As[128 * AS_STRIDE];  // 34,816 B
  u16* t_su = As;                    // [64][136]
  u16* u_su = As + 64 * AS_STRIDE;   // [64][136]

  const int tid = threadIdx.x;
  const int m0 = blockIdx.x * 64;
  const int w = tid >> 6, lane = tid & 63, quad = lane >> 4, l16 = lane & 15;
  const int c0w = w * 32;

  { // stage h (bf16 copy) + aggr (f32 -> bf16), then zero aggr for next layer
    int r = tid >> 4, c8 = (tid & 15) * 8;
    const float4 z4 = {0.f, 0.f, 0.f, 0.f};
    #pragma unroll
    for (int rp = 0; rp < 4; rp++) {
      int m = rp * 16 + r;
      int node = m0 + m; if (node >= Nn) node = Nn - 1;
      *(uint4*)(As + m * AS_STRIDE + c8) = *(const uint4*)(hbf + (size_t)node * 128 + c8);
      float* ap = aggr + (size_t)node * 128 + c8;
      float4 f0 = *(const float4*)ap;
      float4 f1 = *(const float4*)(ap + 4);
      uint4 pk;
      pk.x = cvt2bf(f0.x, f0.y); pk.y = cvt2bf(f0.z, f0.w);
      pk.z = cvt2bf(f1.x, f1.y); pk.w = cvt2bf(f1.z, f1.w);
      *(uint4*)(As + (64 + m) * AS_STRIDE + c8) = pk;
      *(float4*)ap = z4;
      *(float4*)(ap + 4) = z4;
    }
  }
  __syncthreads();

  f32x4 acc[4][2];
  #pragma unroll
  for (int rt = 0; rt < 4; rt++)
    #pragma unroll
    for (int ct = 0; ct < 2; ct++)
      acc[rt][ct] = (f32x4){0.f, 0.f, 0.f, 0.f};

  #pragma unroll
  for (int kk = 0; kk < 8; kk++) {
    const u16* Ab = As + (kk < 4 ? 0 : 64 * AS_STRIDE);
    const int kl = (kk & 3) * 32 + quad * 8;
    bf16x8 af[4];
    #pragma unroll
    for (int rt = 0; rt < 4; rt++)
      af[rt] = *(const bf16x8*)(Ab + (rt * 16 + l16) * AS_STRIDE + kl);
    const int kg = kk * 32 + quad * 8;
    #pragma unroll
    for (int ct = 0; ct < 2; ct++) {
      bf16x8 bfv = *(const bf16x8*)(W1T + (size_t)(c0w + ct * 16 + l16) * 256 + kg);
      #pragma unroll
      for (int rt = 0; rt < 4; rt++)
        acc[rt][ct] = __builtin_amdgcn_mfma_f32_16x16x32_bf16(af[rt], bfv, acc[rt][ct], 0, 0, 0);
    }
  }

  float b1v[2];
  #pragma unroll
  for (int ct = 0; ct < 2; ct++) b1v[ct] = b1[c0w + ct * 16 + l16];
  __syncthreads();

  #pragma unroll
  for (int rt = 0; rt < 4; rt++)
    #pragma unroll
    for (int ct = 0; ct < 2; ct++) {
      int n = c0w + ct * 16 + l16;
      #pragma unroll
      for (int r = 0; r < 4; r++)
        t_su[(rt * 16 + quad * 4 + r) * AS_STRIDE + n] = f2bf1(acc[rt][ct][r] + b1v[ct]);
    }
  __syncthreads();

  { // inner LN + SiLU: read t_su, write u_su
    int row = tid >> 2, sub = tid & 3;
    float s = 0.f, sq = 0.f, vals[32];
    #pragma unroll
    for (int i = 0; i < 32; i++) {
      float v = bf2f(t_su[row * AS_STRIDE + sub + i * 4]);
      vals[i] = v; s += v; sq += v * v;
    }
    s += __shfl_xor(s, 1); sq += __shfl_xor(sq, 1);
    s += __shfl_xor(s, 2); sq += __shfl_xor(sq, 2);
    float mean = s * (1.f / 128.f);
    float rstd = rsq_f(sq * (1.f / 128.f) - mean * mean + 1e-5f);
    #pragma unroll
    for (int i = 0; i < 32; i++) {
      int c = sub + i * 4;
      float a = (vals[i] - mean) * rstd * g[c] + be[c];
      u_su[row * AS_STRIDE + c] = f2bf1(silu_f(a));
    }
  }
  __syncthreads();

  f32x4 acc2[4][2];
  #pragma unroll
  for (int rt = 0; rt < 4; rt++)
    #pragma unroll
    for (int ct = 0; ct < 2; ct++)
      acc2[rt][ct] = (f32x4){0.f, 0.f, 0.f, 0.f};

  #pragma unroll
  for (int kk = 0; kk < 4; kk++) {
    const int kl = kk * 32 + quad * 8;
    bf16x8 af[4];
    #pragma unroll
    for (int rt = 0; rt < 4; rt++)
      af[rt] = *(const bf16x8*)(u_su + (rt * 16 + l16) * AS_STRIDE + kl);
    #pragma unroll
    for (int ct = 0; ct < 2; ct++) {
      bf16x8 bfv = *(const bf16x8*)(W2T + (size_t)(c0w + ct * 16 + l16) * 128 + kl);
      #pragma unroll
      for (int rt = 0; rt < 4; rt++)
        acc2[rt][ct] = __builtin_amdgcn_mfma_f32_16x16x32_bf16(af[rt], bfv, acc2[rt][ct], 0, 0, 0);
    }
  }
  __syncthreads();

  #pragma unroll
  for (int ct = 0; ct < 2; ct++) {
    int n = c0w + ct * 16 + l16;
    float b2v = b2[n];
    #pragma unroll
    for (int rt = 0; rt < 4; rt++)
      #pragma unroll
      for (int r = 0; r < 4; r++) {
        int m = rt * 16 + quad * 4 + r;
        int node = m0 + m; if (node >= Nn) node = Nn - 1;
        t_su[m * AS_STRIDE + n] =
            f2bf1(acc2[rt][ct][r] + b2v + bf2f(hbf[(size_t)node * 128 + n]));
      }
  }
  __syncthreads();

  { // outer LN -> hbf and back into t_su (A-layout h)
    int row = tid >> 2, sub = tid & 3;
    int node = m0 + row;
    float s = 0.f, sq = 0.f, vals[32];
    #pragma unroll
    for (int i = 0; i < 32; i++) {
      float v = bf2f(t_su[row * AS_STRIDE + sub + i * 4]);
      vals[i] = v; s += v; sq += v * v;
    }
    s += __shfl_xor(s, 1); sq += __shfl_xor(sq, 1);
    s += __shfl_xor(s, 2); sq += __shfl_xor(sq, 2);
    float mean = s * (1.f / 128.f);
    float rstd = rsq_f(sq * (1.f / 128.f) - mean * mean + 1e-5f);
    #pragma unroll
    for (int i = 0; i < 32; i++) {
      int c = sub + i * 4;
      float v = (vals[i] - mean) * rstd * lng[c] + lnb[c];
      u16 hb = f2bf1(v);
      t_su[row * AS_STRIDE + c] = hb;
      if (node < Nn) hbf[(size_t)node * 128 + c] = hb;
    }
  }

  if (W1Tn != nullptr) { // fused next-layer hd = h@W1d + b1, hs = h@W1s
    __syncthreads();
    f32x4 ah[4][2];
    #pragma unroll
    for (int rt = 0; rt < 4; rt++)
      #pragma unroll
      for (int ct = 0; ct < 2; ct++)
        ah[rt][ct] = (f32x4){0.f, 0.f, 0.f, 0.f};
    #pragma unroll
    for (int kk = 0; kk < 4; kk++) {
      const int kl = kk * 32 + quad * 8;
      bf16x8 af[4];
      #pragma unroll
      for (int rt = 0; rt < 4; rt++)
        af[rt] = *(const bf16x8*)(t_su + (rt * 16 + l16) * AS_STRIDE + kl);
      #pragma unroll
      for (int ct = 0; ct < 2; ct++) {
        bf16x8 bd = *(const bf16x8*)(W1Tn + (size_t)(c0w + ct * 16 + l16) * 256 + kl);
        #pragma unroll
        for (int rt = 0; rt < 4; rt++)
          ah[rt][ct] = __builtin_amdgcn_mfma_f32_16x16x32_bf16(af[rt], bd, ah[rt][ct], 0, 0, 0);
      }
    }
    #pragma unroll
    for (int ct = 0; ct < 2; ct++) {
      int n = c0w + ct * 16 + l16;
      float bv = b1n[n];
      #pragma unroll
      for (int rt = 0; rt < 4; rt++)
        #pragma unroll
        for (int r = 0; r < 4; r++) {
          int node = m0 + rt * 16 + quad * 4 + r;
          if (node < Nn) hd_all[(size_t)node * 128 + n] = f2bf1(ah[rt][ct][r] + bv);
        }
    }
    #pragma unroll
    for (int rt = 0; rt < 4; rt++)
      #pragma unroll
      for (int ct = 0; ct < 2; ct++)
        ah[rt][ct] = (f32x4){0.f, 0.f, 0.f, 0.f};
    #pragma unroll
    for (int kk = 0; kk < 4; kk++) {
      const int kl = kk * 32 + quad * 8;
      bf16x8 af[4];
      #pragma unroll
      for (int rt = 0; rt < 4; rt++)
        af[rt] = *(const bf16x8*)(t_su + (rt * 16 + l16) * AS_STRIDE + kl);
      #pragma unroll
      for (int ct = 0; ct < 2; ct++) {
        bf16x8 bs = *(const bf16x8*)(W1Tn + (size_t)(c0w + ct * 16 + l16) * 256 + 128 + kl);
        #pragma unroll
        for (int rt = 0; rt < 4; rt++)
          ah[rt][ct] = __builtin_amdgcn_mfma_f32_16x16x32_bf16(af[rt], bs, ah[rt][ct], 0, 0, 0);
      }
    }
    #pragma unroll
    for (int ct = 0; ct < 2; ct++) {
      int n = c0w + ct * 16 + l16;
      #pragma unroll
      for (int rt = 0; rt < 4; rt++)
        #pragma unroll
        for (int r = 0; r < 4; r++) {
          int node = m0 + rt * 16 + quad * 4 + r;
          if (node < Nn) hs_all[(size_t)node * 128 + n] = f2bf1(ah[rt][ct][r]);
        }
    }
  }

  if (dW1T != nullptr) { // fused decoder (layer 2): h in t_su (A-layout)
    __syncthreads();
    f32x4 da[4][2];
    #pragma unroll
    for (int rt = 0; rt < 4; rt++)
      #pragma unroll
      for (int ct = 0; ct < 2; ct++)
        da[rt][ct] = (f32x4){0.f, 0.f, 0.f, 0.f};
    #pragma unroll
    for (int kk = 0; kk < 4; kk++) {
      const int kl = kk * 32 + quad * 8;
      bf16x8 af[4];
      #pragma unroll
      for (int rt = 0; rt < 4; rt++)
        af[rt] = *(const bf16x8*)(t_su + (rt * 16 + l16) * AS_STRIDE + kl);
      #pragma unroll
      for (int ct = 0; ct < 2; ct++) {
        bf16x8 bfv = *(const bf16x8*)(dW1T + (size_t)(c0w + ct * 16 + l16) * 128 + kl);
        #pragma unroll
        for (int rt = 0; rt < 4; rt++)
          da[rt][ct] = __builtin_amdgcn_mfma_f32_16x16x32_bf16(af[rt], bfv, da[rt][ct], 0, 0, 0);
      }
    }
    __syncthreads();
    #pragma unroll
    for (int ct = 0; ct < 2; ct++) {
      int n = c0w + ct * 16 + l16;
      float bv = db1[n];
      #pragma unroll
      for (int rt = 0; rt < 4; rt++)
        #pragma unroll
        for (int r = 0; r < 4; r++)
          u_su[(rt * 16 + quad * 4 + r) * AS_STRIDE + n] = f2bf1(silu_f(da[rt][ct][r] + bv));
    }
    __syncthreads();
    { // dec L2: 64 cols, wave covers 16; u2 overwrites t_su region
      const int c0b = w * 16;
      f32x4 a2[4];
      #pragma unroll
      for (int rt = 0; rt < 4; rt++) a2[rt] = (f32x4){0.f, 0.f, 0.f, 0.f};
      #pragma unroll
      for (int kk = 0; kk < 4; kk++) {
        const int kl = kk * 32 + quad * 8;
        bf16x8 af[4];
        #pragma unroll
        for (int rt = 0; rt < 4; rt++)
          af[rt] = *(const bf16x8*)(u_su + (rt * 16 + l16) * AS_STRIDE + kl);
        bf16x8 bfv = *(const bf16x8*)(dW2T + (size_t)(c0b + l16) * 128 + kl);
        #pragma unroll
        for (int rt = 0; rt < 4; rt++)
          a2[rt] = __builtin_amdgcn_mfma_f32_16x16x32_bf16(af[rt], bfv, a2[rt], 0, 0, 0);
      }
      float bv = db2[c0b + l16];
      #pragma unroll
      for (int rt = 0; rt < 4; rt++)
        #pragma unroll
        for (int r = 0; r < 4; r++)
          t_su[(rt * 16 + quad * 4 + r) * 72 + c0b + l16] = f2bf1(silu_f(a2[rt][r] + bv));
    }
    __syncthreads();
    if (w == 0) { // dec L3: 6 cols (padded 16), K=64
      f32x4 a3[4];
      #pragma unroll
      for (int rt = 0; rt < 4; rt++) a3[rt] = (f32x4){0.f, 0.f, 0.f, 0.f};
      #pragma unroll
      for (int kk = 0; kk < 2; kk++) {
        const int kl = kk * 32 + quad * 8;
        bf16x8 af[4];
        #pragma unroll
        for (int rt = 0; rt < 4; rt++)
          af[rt] = *(const bf16x8*)(t_su + (rt * 16 + l16) * 72 + kl);
        bf16x8 bfv = *(const bf16x8*)(dW3T + l16 * 64 + kl);
        #pragma unroll
        for (int rt = 0; rt < 4; rt++)
          a3[rt] = __builtin_amdgcn_mfma_f32_16x16x32_bf16(af[rt], bfv, a3[rt], 0, 0, 0);
      }
      if (l16 < 6) {
        float bv = db3[l16];
        #pragma unroll
        for (int rt = 0; rt < 4; rt++)
          #pragma unroll
          for (int r = 0; r < 4; r++) {
            int node = m0 + rt * 16 + quad * 4 + r;
            if (node < Nn)
              out[(size_t)node * 6 + l16] = a3[rt][r] + bv + x[node * 7 + l16];
          }
      }
    }
  }
}

// ---------------- host launcher ----------------------------------------------
extern "C" void kernel_launch(void* const* d_in, const int* in_sizes, int n_in,
                              void* d_out, int out_size, void* d_ws, size_t ws_size,
                              hipStream_t stream) {
  const float* x      = (const float*)d_in[0];
  const float* pos    = (const float*)d_in[1];
  const int*   eidx   = (const int*)d_in[2];
  const float* enc_w1 = (const float*)d_in[3];
  const float* enc_b1 = (const float*)d_in[4];
  const float* enc_g  = (const float*)d_in[5];
  const float* enc_be = (const float*)d_in[6];
  const float* enc_w2 = (const float*)d_in[7];
  const float* enc_b2 = (const float*)d_in[8];
  const float* e_w1   = (const float*)d_in[9];
  const float* e_b1   = (const float*)d_in[10];
  const float* e_g    = (const float*)d_in[11];
  const float* e_be   = (const float*)d_in[12];
  const float* e_w2   = (const float*)d_in[13];
  const float* e_b2   = (const float*)d_in[14];
  const float* n_w1   = (const float*)d_in[15];
  const float* n_b1   = (const float*)d_in[16];
  const float* n_g    = (const float*)d_in[17];
  const float* n_be   = (const float*)d_in[18];
  const float* n_w2   = (const float*)d_in[19];
  const float* n_b2   = (const float*)d_in[20];
  const float* ln_g   = (const float*)d_in[21];
  const float* ln_b   = (const float*)d_in[22];
  const float* dec_w1 = (const float*)d_in[23];
  const float* dec_b1 = (const float*)d_in[24];
  const float* dec_w2 = (const float*)d_in[25];
  const float* dec_b2 = (const float*)d_in[26];
  const float* dec_w3 = (const float*)d_in[27];
  const float* dec_b3 = (const float*)d_in[28];

  const int N = in_sizes[0] / 7;          // 50000
  const int E = in_sizes[2] / 2;          // 1600000

  char* ws = (char*)d_ws;
  size_t off = 0;
  u16*   hbf    = (u16*)(ws + off);   off += (size_t)N * 128 * 2;
  u16*   hd_all = (u16*)(ws + off);   off += (size_t)N * 128 * 2;
  u16*   hs_all = (u16*)(ws + off);   off += (size_t)N * 128 * 2;
  float* aggr   = (float*)(ws + off); off += (size_t)N * 128 * 4;
  u16* eW1T = (u16*)(ws + off); off += 3 * 128 * 256 * 2;
  u16* eW2T = (u16*)(ws + off); off += 3 * 128 * 128 * 2;
  u16* nW1T = (u16*)(ws + off); off += 3 * 128 * 256 * 2;
  u16* nW2T = (u16*)(ws + off); off += 3 * 128 * 128 * 2;
  u16* encW1T = (u16*)(ws + off); off += 128 * 32 * 2;
  u16* encW2T = (u16*)(ws + off); off += 128 * 128 * 2;
  u16* decW1T = (u16*)(ws + off); off += 128 * 128 * 2;
  u16* decW2T = (u16*)(ws + off); off += 64 * 128 * 2;
  u16* decW3T = (u16*)(ws + off); off += 16 * 64 * 2;
  int* cnt    = (int*)(ws + off); off += (size_t)N * 4;
  int* cursor = (int*)(ws + off); off += (size_t)N * 4;
  int* ssrc   = (int*)(ws + off); off += (size_t)E * 4;
  int* sdst   = (int*)(ws + off); off += (size_t)E * 4;

  // sort edges by dst once (reused across all 3 layers)
  hipMemsetAsync(cnt, 0, (size_t)N * 4, stream);
  edge_hist<<<(E + 255) / 256, 256, 0, stream>>>(eidx + E, E, cnt);
  scan_kernel<<<1, 1024, 0, stream>>>(cnt, cursor, N);
  edge_scatter<<<(E + 255) / 256, 256, 0, stream>>>(eidx, eidx + E, E, cursor, ssrc, sdst);

  prep_weights<<<1152, 256, 0, stream>>>(e_w1, e_w2, n_w1, n_w2, eW1T, eW2T, nW1T, nW2T);
  prep_weights2<<<180, 256, 0, stream>>>(enc_w1, enc_w2, dec_w1, dec_w2, dec_w3,
                                         encW1T, encW2T, decW1T, decW2T, decW3T);

  // zero aggr ONCE; node_mlp re-zeroes its rows for the next layer after reading
  hipMemsetAsync(aggr, 0, (size_t)N * 128 * 4, stream);

  const int nblk = (N + 63) / 64;
  encoder_mfma<<<nblk, 256, 0, stream>>>(x, encW1T, enc_b1, enc_g, enc_be, encW2T, enc_b2,
                                         eW1T, e_b1, hbf, hd_all, hs_all, N);

  for (int l = 0; l < 3; l++) {
    edge_mlp_kernel<<<E / 64, 256, 0, stream>>>(
        ssrc, sdst, pos, hd_all, hs_all,
        e_w1 + (size_t)l * 33408 + 256 * 128,   // W1c rows as f32 [5][128]
        e_g + l * 128, e_be + l * 128,
        eW2T + (size_t)l * 128 * 128, e_b2 + l * 128, aggr);
    const u16* W1Tn = (l < 2) ? (eW1T + (size_t)(l + 1) * 128 * 256) : (const u16*)nullptr;
    const bool last = (l == 2);
    node_mlp_kernel<<<nblk, 256, 0, stream>>>(
        hbf, aggr,
        nW1T + (size_t)l * 128 * 256, n_b1 + l * 128, n_g + l * 128, n_be + l * 128,
        nW2T + (size_t)l * 128 * 128, n_b2 + l * 128,
        ln_g + l * 128, ln_b + l * 128,
        W1Tn, e_b1 + ((l + 1) % 3) * 128, hd_all, hs_all,
        x,
        last ? decW1T : (const u16*)nullptr, dec_b1,
        last ? decW2T : (const u16*)nullptr, dec_b2,
        last ? decW3T : (const u16*)nullptr, dec_b3,
        (float*)d_out, N);
  }
}

// Round 10
// 1114.972 us; speedup vs baseline: 1.7369x; 1.0285x over previous
//
#include <hip/hip_runtime.h>

typedef unsigned short u16;
typedef unsigned int u32;
typedef __bf16 bf16x8 __attribute__((ext_vector_type(8)));
typedef float f32x4 __attribute__((ext_vector_type(4)));
typedef float f32x2 __attribute__((ext_vector_type(2)));

#define AS_STRIDE 136   // bf16 elems per LDS A-row (128 + 8 pad; 16B-aligned rows)

__device__ __forceinline__ u16 f2bf1(float f) {
  union { __bf16 h; u16 u; } c; c.h = (__bf16)f; return c.u;
}
__device__ __forceinline__ u32 cvt2bf(float a, float b) {
  union { __bf16 h[2]; u32 u; } c; c.h[0] = (__bf16)a; c.h[1] = (__bf16)b; return c.u;
}
__device__ __forceinline__ float bf2f(u16 u) {
  union { u32 u; float f; } v; v.u = ((u32)u) << 16; return v.f;
}
// silu via v_rcp_f32 (2 ops) instead of IEEE f32 divide (~10-op sequence)
__device__ __forceinline__ float silu_f(float a) {
  return a * __builtin_amdgcn_rcpf(1.f + __expf(-a));
}
__device__ __forceinline__ float rsq_f(float x) {
  return __builtin_amdgcn_rsqf(x);
}
__device__ __forceinline__ f32x2 unpk2(u32 p) {
  union { u32 u; float f; } a, b;
  a.u = p << 16; b.u = p & 0xffff0000u;
  return (f32x2){a.f, b.f};
}
// involution mapping LDS row -> sorted-edge index: swaps the rt and quad fields
// P(rt*16 + quad*4 + r) = quad*16 + rt*4 + r  (P(P(i)) == i)
__device__ __forceinline__ int permP(int i) {
  return ((i >> 2) & 3) * 16 + ((i >> 4) & 3) * 4 + (i & 3);
}

// ---------------- edge sort by dst (counting sort, once per call) ------------
__global__ void edge_hist(const int* __restrict__ edst, int E, int* __restrict__ cnt) {
  int i = blockIdx.x * blockDim.x + threadIdx.x;
  if (i < E) atomicAdd(&cnt[edst[i]], 1);
}

__global__ __launch_bounds__(1024)
void scan_kernel(const int* __restrict__ cnt, int* __restrict__ cursor, int Nn) {
  __shared__ int part[1024];
  int t = threadIdx.x;
  int per = (Nn + 1023) / 1024;
  int b = t * per;
  int s = 0;
  for (int i = 0; i < per; i++) { int idx = b + i; if (idx < Nn) s += cnt[idx]; }
  part[t] = s;
  __syncthreads();
  for (int d = 1; d < 1024; d <<= 1) {
    int v = (t >= d) ? part[t - d] : 0;
    __syncthreads();
    part[t] += v;
    __syncthreads();
  }
  int excl = (t == 0) ? 0 : part[t - 1];
  for (int i = 0; i < per; i++) {
    int idx = b + i;
    if (idx < Nn) { cursor[idx] = excl; excl += cnt[idx]; }
  }
}

// r13: single int2 store per edge (was 2x4B to two regions) -> halves the
// scattered-HBM-line count of the sort (r7 counters: scatter WRITE ~145MB).
__global__ void edge_scatter(const int* __restrict__ esrc, const int* __restrict__ edst,
                             int E, int* __restrict__ cursor,
                             int2* __restrict__ sedge) {
  int i = blockIdx.x * blockDim.x + threadIdx.x;
  if (i < E) {
    int d = edst[i];
    int p = atomicAdd(&cursor[d], 1);
    sedge[p] = make_int2(esrc[i], d);
  }
}

// ---------------- weight prep: transpose + bf16-cast -------------------------
__global__ void prep_weights(const float* __restrict__ e_w1, const float* __restrict__ e_w2,
                             const float* __restrict__ n_w1, const float* __restrict__ n_w2,
                             u16* __restrict__ eW1T, u16* __restrict__ eW2T,
                             u16* __restrict__ nW1T, u16* __restrict__ nW2T) {
  int i = blockIdx.x * blockDim.x + threadIdx.x;
  const int s1 = 3 * 128 * 256;
  const int s2 = 3 * 128 * 128;
  if (i < s1) {
    int l = i / 32768, r = i % 32768, n = r >> 8, k = r & 255;
    eW1T[i] = f2bf1(e_w1[l * 33408 + k * 128 + n]);
  } else if (i < s1 + s2) {
    int j = i - s1; int l = j / 16384, r = j % 16384, n = r >> 7, k = r & 127;
    eW2T[j] = f2bf1(e_w2[l * 16384 + k * 128 + n]);
  } else if (i < s1 + s2 + s1) {
    int j = i - s1 - s2; int l = j / 32768, r = j % 32768, n = r >> 8, k = r & 255;
    nW1T[j] = f2bf1(n_w1[l * 32768 + k * 128 + n]);
  } else if (i < 2 * s1 + 2 * s2) {
    int j = i - 2 * s1 - s2; int l = j / 16384, r = j % 16384, n = r >> 7, k = r & 127;
    nW2T[j] = f2bf1(n_w2[l * 16384 + k * 128 + n]);
  }
}

// enc/dec weights (edge-attr weight consumed as f32 directly from e_w1)
__global__ void prep_weights2(const float* __restrict__ enc_w1, const float* __restrict__ enc_w2,
                              const float* __restrict__ dec_w1, const float* __restrict__ dec_w2,
                              const float* __restrict__ dec_w3,
                              u16* __restrict__ encW1T, u16* __restrict__ encW2T,
                              u16* __restrict__ decW1T, u16* __restrict__ decW2T,
                              u16* __restrict__ decW3T) {
  int i = blockIdx.x * blockDim.x + threadIdx.x;
  if (i < 4096) {
    int n = i >> 5, k = i & 31;
    encW1T[i] = (k < 7) ? f2bf1(enc_w1[k * 128 + n]) : (u16)0;
  } else if (i < 20480) {
    int j = i - 4096; int n = j >> 7, k = j & 127;
    encW2T[j] = f2bf1(enc_w2[k * 128 + n]);
  } else if (i < 36864) {
    int j = i - 20480; int n = j >> 7, k = j & 127;
    decW1T[j] = f2bf1(dec_w1[k * 128 + n]);
  } else if (i < 45056) {
    int j = i - 36864; int n = j >> 7, k = j & 127;
    decW2T[j] = f2bf1(dec_w2[k * 64 + n]);
  } else if (i < 46080) {
    int j = i - 45056; int n = j >> 6, k = j & 63;
    decW3T[j] = (n < 6) ? f2bf1(dec_w3[k * 6 + n]) : (u16)0;
  }
}

// ---------------- encoder (MFMA) + fused hd/hs for layer 0 -------------------
__global__ __launch_bounds__(256, 4)
void encoder_mfma(const float* __restrict__ x,
                  const u16* __restrict__ W1T,   // [128][32]
                  const float* __restrict__ b1,
                  const float* __restrict__ g, const float* __restrict__ be,
                  const u16* __restrict__ W2T,   // [128][128]
                  const float* __restrict__ b2,
                  const u16* __restrict__ eW1T0, // [128][256] layer-0 edge W1
                  const float* __restrict__ eb10,
                  u16* __restrict__ hbf, u16* __restrict__ hd_all,
                  u16* __restrict__ hs_all, int Nn) {
  __shared__ __align__(16) u16 As[64 * 40];
  __shared__ __align__(16) u16 ts[64 * AS_STRIDE];
  const int tid = threadIdx.x;
  const int m0 = blockIdx.x * 64;
  const int w = tid >> 6, lane = tid & 63, quad = lane >> 4, l16 = lane & 15;
  const int c0w = w * 32;

  if (tid < 64) {
    int node = m0 + tid; if (node >= Nn) node = Nn - 1;
    union { u16 us[32]; uint4 v[4]; } pk;
    #pragma unroll
    for (int k = 0; k < 32; k++) pk.us[k] = 0;
    #pragma unroll
    for (int k = 0; k < 7; k++) pk.us[k] = f2bf1(x[node * 7 + k]);
    #pragma unroll
    for (int k = 0; k < 4; k++) *(uint4*)(As + tid * 40 + k * 8) = pk.v[k];
  }
  __syncthreads();

  f32x4 acc[4][2];
  #pragma unroll
  for (int rt = 0; rt < 4; rt++)
    #pragma unroll
    for (int ct = 0; ct < 2; ct++)
      acc[rt][ct] = (f32x4){0.f, 0.f, 0.f, 0.f};
  {
    const int kl = quad * 8;
    bf16x8 af[4];
    #pragma unroll
    for (int rt = 0; rt < 4; rt++)
      af[rt] = *(const bf16x8*)(As + (rt * 16 + l16) * 40 + kl);
    #pragma unroll
    for (int ct = 0; ct < 2; ct++) {
      bf16x8 bfv = *(const bf16x8*)(W1T + (c0w + ct * 16 + l16) * 32 + kl);
      #pragma unroll
      for (int rt = 0; rt < 4; rt++)
        acc[rt][ct] = __builtin_amdgcn_mfma_f32_16x16x32_bf16(af[rt], bfv, acc[rt][ct], 0, 0, 0);
    }
  }
  #pragma unroll
  for (int ct = 0; ct < 2; ct++) {
    int n = c0w + ct * 16 + l16;
    float b1v = b1[n];
    #pragma unroll
    for (int rt = 0; rt < 4; rt++)
      #pragma unroll
      for (int r = 0; r < 4; r++)
        ts[(rt * 16 + quad * 4 + r) * AS_STRIDE + n] = f2bf1(acc[rt][ct][r] + b1v);
  }
  __syncthreads();

  { // LN + SiLU in place (bf16)
    int row = tid >> 2, sub = tid & 3;
    float s = 0.f, sq = 0.f, vals[32];
    #pragma unroll
    for (int i = 0; i < 32; i++) {
      float v = bf2f(ts[row * AS_STRIDE + sub + i * 4]);
      vals[i] = v; s += v; sq += v * v;
    }
    s += __shfl_xor(s, 1); sq += __shfl_xor(sq, 1);
    s += __shfl_xor(s, 2); sq += __shfl_xor(sq, 2);
    float mean = s * (1.f / 128.f);
    float rstd = rsq_f(sq * (1.f / 128.f) - mean * mean + 1e-5f);
    #pragma unroll
    for (int i = 0; i < 32; i++) {
      int c = sub + i * 4;
      float a = (vals[i] - mean) * rstd * g[c] + be[c];
      ts[row * AS_STRIDE + c] = f2bf1(silu_f(a));
    }
  }
  __syncthreads();

  f32x4 acc2[4][2];
  #pragma unroll
  for (int rt = 0; rt < 4; rt++)
    #pragma unroll
    for (int ct = 0; ct < 2; ct++)
      acc2[rt][ct] = (f32x4){0.f, 0.f, 0.f, 0.f};
  #pragma unroll
  for (int kk = 0; kk < 4; kk++) {
    const int kl = kk * 32 + quad * 8;
    bf16x8 af[4];
    #pragma unroll
    for (int rt = 0; rt < 4; rt++)
      af[rt] = *(const bf16x8*)(ts + (rt * 16 + l16) * AS_STRIDE + kl);
    #pragma unroll
    for (int ct = 0; ct < 2; ct++) {
      bf16x8 bfv = *(const bf16x8*)(W2T + (size_t)(c0w + ct * 16 + l16) * 128 + kl);
      #pragma unroll
      for (int rt = 0; rt < 4; rt++)
        acc2[rt][ct] = __builtin_amdgcn_mfma_f32_16x16x32_bf16(af[rt], bfv, acc2[rt][ct], 0, 0, 0);
    }
  }
  __syncthreads();   // ts reads done; rewrite with h
  #pragma unroll
  for (int ct = 0; ct < 2; ct++) {
    int n = c0w + ct * 16 + l16;
    float b2v = b2[n];
    #pragma unroll
    for (int rt = 0; rt < 4; rt++)
      #pragma unroll
      for (int r = 0; r < 4; r++) {
        int m = rt * 16 + quad * 4 + r;
        int node = m0 + m;
        u16 hb = f2bf1(acc2[rt][ct][r] + b2v);
        ts[m * AS_STRIDE + n] = hb;
        if (node < Nn) hbf[(size_t)node * 128 + n] = hb;
      }
  }
  __syncthreads();

  { // fused hd = h@W1d + b1, then hs = h@W1s (layer 0)
    f32x4 ah[4][2];
    #pragma unroll
    for (int rt = 0; rt < 4; rt++)
      #pragma unroll
      for (int ct = 0; ct < 2; ct++)
        ah[rt][ct] = (f32x4){0.f, 0.f, 0.f, 0.f};
    #pragma unroll
    for (int kk = 0; kk < 4; kk++) {
      const int kl = kk * 32 + quad * 8;
      bf16x8 af[4];
      #pragma unroll
      for (int rt = 0; rt < 4; rt++)
        af[rt] = *(const bf16x8*)(ts + (rt * 16 + l16) * AS_STRIDE + kl);
      #pragma unroll
      for (int ct = 0; ct < 2; ct++) {
        bf16x8 bd = *(const bf16x8*)(eW1T0 + (size_t)(c0w + ct * 16 + l16) * 256 + kl);
        #pragma unroll
        for (int rt = 0; rt < 4; rt++)
          ah[rt][ct] = __builtin_amdgcn_mfma_f32_16x16x32_bf16(af[rt], bd, ah[rt][ct], 0, 0, 0);
      }
    }
    #pragma unroll
    for (int ct = 0; ct < 2; ct++) {
      int n = c0w + ct * 16 + l16;
      float b1v = eb10[n];
      #pragma unroll
      for (int rt = 0; rt < 4; rt++)
        #pragma unroll
        for (int r = 0; r < 4; r++) {
          int node = m0 + rt * 16 + quad * 4 + r;
          if (node < Nn) hd_all[(size_t)node * 128 + n] = f2bf1(ah[rt][ct][r] + b1v);
        }
    }
    #pragma unroll
    for (int rt = 0; rt < 4; rt++)
      #pragma unroll
      for (int ct = 0; ct < 2; ct++)
        ah[rt][ct] = (f32x4){0.f, 0.f, 0.f, 0.f};
    #pragma unroll
    for (int kk = 0; kk < 4; kk++) {
      const int kl = kk * 32 + quad * 8;
      bf16x8 af[4];
      #pragma unroll
      for (int rt = 0; rt < 4; rt++)
        af[rt] = *(const bf16x8*)(ts + (rt * 16 + l16) * AS_STRIDE + kl);
      #pragma unroll
      for (int ct = 0; ct < 2; ct++) {
        bf16x8 bs = *(const bf16x8*)(eW1T0 + (size_t)(c0w + ct * 16 + l16) * 256 + 128 + kl);
        #pragma unroll
        for (int rt = 0; rt < 4; rt++)
          ah[rt][ct] = __builtin_amdgcn_mfma_f32_16x16x32_bf16(af[rt], bs, ah[rt][ct], 0, 0, 0);
      }
    }
    #pragma unroll
    for (int ct = 0; ct < 2; ct++) {
      int n = c0w + ct * 16 + l16;
      #pragma unroll
      for (int rt = 0; rt < 4; rt++)
        #pragma unroll
        for (int r = 0; r < 4; r++) {
          int node = m0 + rt * 16 + quad * 4 + r;
          if (node < Nn) hs_all[(size_t)node * 128 + n] = f2bf1(ah[rt][ct][r]);
        }
    }
  }
}

// ---------------- edge MLP: rank-5 ea term in registers, 7 blk/CU ------------
// r13 = r12 (edge 200.6us verified) + merged 2-col flush (one cmp chain drives
// both ct accumulators) + b2 folded to node via cnt (r7-verified) + int2 edges.
__global__ __launch_bounds__(256, 7)
void edge_mlp_kernel(const int2* __restrict__ sedge,
                     const float* __restrict__ pos,
                     const u16* __restrict__ hd_all, const u16* __restrict__ hs_all,
                     const float* __restrict__ w1cF, // [5][128] f32 (= e_w1 rows 256..260)
                     const float* __restrict__ g, const float* __restrict__ be,
                     const u16* __restrict__ W2T,   // [128][128] bf16
                     float* __restrict__ aggr) {
  __shared__ int s_dst[64];                           // dst of SORTED edge e0+i
  __shared__ __align__(16) float s_ea[64 * 8];        // ea feats f32, row i = edge P(i)
  __shared__ __align__(16) float s_w1c[5 * 128];      // W1c f32
  __shared__ __align__(16) u16 s_t[64 * AS_STRIDE];   // u (row i = edge P(i))

  const int tid = threadIdx.x;
  // XCD swizzle: consecutive-dst chunks stay on one XCD
  const int bid = blockIdx.x;
  const int e0 = ((bid & 7) * (gridDim.x >> 3) + (bid >> 3)) * 64;
  const int w = tid >> 6, lane = tid & 63, quad = lane >> 4, l16 = lane & 15;
  const int c0w = w * 32;
  const int rg = tid >> 4, cg = tid & 15;
  const int c0 = cg * 8;

  // ---- prefetch ALL phase-A gathers at kernel top; fence pins issue order ----
  int pdst[4], psrc[4];
  #pragma unroll
  for (int rr = 0; rr < 4; rr++) {
    int j = permP(rg * 4 + rr);          // LDS row rg*4+rr holds edge e0+P(row)
    int2 e = sedge[e0 + j];
    psrc[rr] = e.x;
    pdst[rr] = e.y;
  }
  uint4 hd4[4], hs4[4];
  #pragma unroll
  for (int rr = 0; rr < 4; rr++) {
    hd4[rr] = *(const uint4*)(hd_all + (size_t)pdst[rr] * 128 + c0);
    hs4[rr] = *(const uint4*)(hs_all + (size_t)psrc[rr] * 128 + c0);
  }
  asm volatile("" ::: "memory");  // compiler fence: loads cannot sink below

  if (tid < 64) {
    int jp = permP(tid);
    int2 ej = sedge[e0 + jp];
    int src = ej.x, dst = ej.y;
    s_dst[tid] = sedge[e0 + tid].y;       // sorted order, for the atomic flush
    float dx = pos[dst * 3 + 0] - pos[src * 3 + 0];
    float dy = pos[dst * 3 + 1] - pos[src * 3 + 1];
    float dz = pos[dst * 3 + 2] - pos[src * 3 + 2];
    float dist = sqrtf(dx * dx + dy * dy + dz * dz) + 1e-8f;
    float inv = __builtin_amdgcn_rcpf(dist);
    s_ea[tid * 8 + 0] = dist;
    s_ea[tid * 8 + 1] = dx * inv;
    s_ea[tid * 8 + 2] = dy * inv;
    s_ea[tid * 8 + 3] = dz * inv;
    s_ea[tid * 8 + 4] = __builtin_amdgcn_rcpf(dist * dist + 1e-6f);
  }
  if (tid < 160) *(float4*)(s_w1c + tid * 4) = *(const float4*)(w1cF + tid * 4);
  __syncthreads();

  { // phase A: t = hd[dst] + hs[src] + ea@W1c (rank-5, f32); LN+SiLU -> u in s_t
    f32x2 t2a[4][4];
    #pragma unroll
    for (int rr = 0; rr < 4; rr++) {
      u32 hp[4] = {hd4[rr].x, hd4[rr].y, hd4[rr].z, hd4[rr].w};
      u32 sp[4] = {hs4[rr].x, hs4[rr].y, hs4[rr].z, hs4[rr].w};
      #pragma unroll
      for (int p = 0; p < 4; p++)
        t2a[rr][p] = unpk2(hp[p]) + unpk2(sp[p]);
    }
    #pragma unroll
    for (int k = 0; k < 5; k++) {
      f32x4 wa = *(const f32x4*)(s_w1c + k * 128 + c0);
      f32x4 wb = *(const f32x4*)(s_w1c + k * 128 + c0 + 4);
      f32x2 wk0 = (f32x2){wa[0], wa[1]}, wk1 = (f32x2){wa[2], wa[3]};
      f32x2 wk2 = (f32x2){wb[0], wb[1]}, wk3 = (f32x2){wb[2], wb[3]};
      #pragma unroll
      for (int rr = 0; rr < 4; rr++) {
        float e = s_ea[(rg * 4 + rr) * 8 + k];
        f32x2 ev = (f32x2){e, e};
        t2a[rr][0] += ev * wk0;
        t2a[rr][1] += ev * wk1;
        t2a[rr][2] += ev * wk2;
        t2a[rr][3] += ev * wk3;
      }
    }
    f32x2 g2[4], be2[4];
    {
      f32x4 ga = *(const f32x4*)(g + c0), gb = *(const f32x4*)(g + c0 + 4);
      f32x4 ba = *(const f32x4*)(be + c0), bb = *(const f32x4*)(be + c0 + 4);
      g2[0] = (f32x2){ga[0], ga[1]}; g2[1] = (f32x2){ga[2], ga[3]};
      g2[2] = (f32x2){gb[0], gb[1]}; g2[3] = (f32x2){gb[2], gb[3]};
      be2[0] = (f32x2){ba[0], ba[1]}; be2[1] = (f32x2){ba[2], ba[3]};
      be2[2] = (f32x2){bb[0], bb[1]}; be2[3] = (f32x2){bb[2], bb[3]};
    }
    #pragma unroll
    for (int rr = 0; rr < 4; rr++) {
      int m = rg * 4 + rr;
      f32x2 sm2 = (f32x2){0.f, 0.f}, sq2 = (f32x2){0.f, 0.f};
      #pragma unroll
      for (int p = 0; p < 4; p++) {
        sm2 += t2a[rr][p];
        sq2 += t2a[rr][p] * t2a[rr][p];
      }
      float sm = sm2[0] + sm2[1], sq = sq2[0] + sq2[1];
      sm += __shfl_xor(sm, 1);  sq += __shfl_xor(sq, 1);
      sm += __shfl_xor(sm, 2);  sq += __shfl_xor(sq, 2);
      sm += __shfl_xor(sm, 4);  sq += __shfl_xor(sq, 4);
      sm += __shfl_xor(sm, 8);  sq += __shfl_xor(sq, 8);
      float mean = sm * (1.f / 128.f);
      float rstd = rsq_f(sq * (1.f / 128.f) - mean * mean + 1e-5f);
      f32x2 sc = (f32x2){rstd, rstd};
      f32x2 ofs = (f32x2){-mean * rstd, -mean * rstd};
      float o[8];
      #pragma unroll
      for (int p = 0; p < 4; p++) {
        f32x2 a = t2a[rr][p] * sc + ofs;
        a = a * g2[p] + be2[p];
        o[2 * p]     = silu_f(a[0]);
        o[2 * p + 1] = silu_f(a[1]);
      }
      uint4 st;
      st.x = cvt2bf(o[0], o[1]); st.y = cvt2bf(o[2], o[3]);
      st.z = cvt2bf(o[4], o[5]); st.w = cvt2bf(o[6], o[7]);
      *(uint4*)(s_t + m * AS_STRIDE + c0) = st;
    }
  }
  __syncthreads();

  f32x4 acc2[4][2];
  #pragma unroll
  for (int rt = 0; rt < 4; rt++)
    #pragma unroll
    for (int ct = 0; ct < 2; ct++)
      acc2[rt][ct] = (f32x4){0.f, 0.f, 0.f, 0.f};

  #pragma unroll
  for (int kk = 0; kk < 4; kk++) {               // K=128
    const int kl = kk * 32 + quad * 8;
    bf16x8 af[4];
    #pragma unroll
    for (int rt = 0; rt < 4; rt++)
      af[rt] = *(const bf16x8*)(s_t + (rt * 16 + l16) * AS_STRIDE + kl);
    #pragma unroll
    for (int ct = 0; ct < 2; ct++) {
      bf16x8 bfv = *(const bf16x8*)(W2T + (size_t)(c0w + ct * 16 + l16) * 128 + kl);
      #pragma unroll
      for (int rt = 0; rt < 4; rt++)
        acc2[rt][ct] = __builtin_amdgcn_mfma_f32_16x16x32_bf16(af[rt], bfv, acc2[rt][ct], 0, 0, 0);
    }
  }

  { // merged direct-from-register flush: acc2 row rt*16+quad*4+r holds sorted
    // edge quad*16 + rt*4 + r -> 16 CONTIGUOUS edges; ONE cmp chain drives both
    // ct columns. b2 dropped here; node adds cnt[dst]*b2 (verified r7).
    int dv[16];
    #pragma unroll
    for (int j = 0; j < 16; j++) dv[j] = s_dst[quad * 16 + j];

    float* ap0 = aggr + (c0w + l16);
    float* ap1 = aggr + (c0w + 16 + l16);
    int cur = dv[0];
    float run0 = 0.f, run1 = 0.f;
    #pragma unroll
    for (int j = 0; j < 16; j++) {
      if (dv[j] != cur) {
        atomicAdd(ap0 + (size_t)cur * 128, run0);
        atomicAdd(ap1 + (size_t)cur * 128, run1);
        run0 = 0.f; run1 = 0.f; cur = dv[j];
      }
      run0 += acc2[j >> 2][0][j & 3];
      run1 += acc2[j >> 2][1][j & 3];
    }
    atomicAdd(ap0 + (size_t)cur * 128, run0);
    atomicAdd(ap1 + (size_t)cur * 128, run1);
  }
}

// ------ node MLP + residual + outer LN + fused next hd/hs OR fused decoder ---
__global__ __launch_bounds__(256, 4)
void node_mlp_kernel(u16* __restrict__ hbf, float* __restrict__ aggr,
                     const int* __restrict__ cnt, const float* __restrict__ eb2,
                     const u16* __restrict__ W1T, const float* __restrict__ b1,
                     const float* __restrict__ g, const float* __restrict__ be,
                     const u16* __restrict__ W2T, const float* __restrict__ b2,
                     const float* __restrict__ lng, const float* __restrict__ lnb,
                     const u16* __restrict__ W1Tn, const float* __restrict__ b1n,
                     u16* __restrict__ hd_all, u16* __restrict__ hs_all,
                     const float* __restrict__ x,
                     const u16* __restrict__ dW1T, const float* __restrict__ db1,
                     const u16* __restrict__ dW2T, const float* __restrict__ db2,
                     const u16* __restrict__ dW3T, const float* __restrict__ db3,
                     float* __restrict__ out,
                     int Nn) {
  __shared__ __align__(16) u16 As[128 * AS_STRIDE];  // 34,816 B
  u16* t_su = As;                    // [64][136]
  u16* u_su = As + 64 * AS_STRIDE;   // [64][136]

  const int tid = threadIdx.x;
  const int m0 = blockIdx.x * 64;
  const int w = tid >> 6, lane = tid & 63, quad = lane >> 4, l16 = lane & 15;
  const int c0w = w * 32;

  { // stage h (bf16 copy) + aggr (+cnt*b2e, f32 -> bf16), then zero aggr
    int r = tid >> 4, c8 = (tid & 15) * 8;
    const float4 z4 = {0.f, 0.f, 0.f, 0.f};
    const float4 e0 = *(const float4*)(eb2 + c8);
    const float4 e1 = *(const float4*)(eb2 + c8 + 4);
    #pragma unroll
    for (int rp = 0; rp < 4; rp++) {
      int m = rp * 16 + r;
      int node = m0 + m; if (node >= Nn) node = Nn - 1;
      *(uint4*)(As + m * AS_STRIDE + c8) = *(const uint4*)(hbf + (size_t)node * 128 + c8);
      float* ap = aggr + (size_t)node * 128 + c8;
      float cf = (float)cnt[node];   // aggr_true = aggr + cnt[dst]*b2 (b2 dropped in edge)
      float4 f0 = *(const float4*)ap;
      float4 f1 = *(const float4*)(ap + 4);
      f0.x += cf * e0.x; f0.y += cf * e0.y; f0.z += cf * e0.z; f0.w += cf * e0.w;
      f1.x += cf * e1.x; f1.y += cf * e1.y; f1.z += cf * e1.z; f1.w += cf * e1.w;
      uint4 pk;
      pk.x = cvt2bf(f0.x, f0.y); pk.y = cvt2bf(f0.z, f0.w);
      pk.z = cvt2bf(f1.x, f1.y); pk.w = cvt2bf(f1.z, f1.w);
      *(uint4*)(As + (64 + m) * AS_STRIDE + c8) = pk;
      *(float4*)ap = z4;
      *(float4*)(ap + 4) = z4;
    }
  }
  __syncthreads();

  f32x4 acc[4][2];
  #pragma unroll
  for (int rt = 0; rt < 4; rt++)
    #pragma unroll
    for (int ct = 0; ct < 2; ct++)
      acc[rt][ct] = (f32x4){0.f, 0.f, 0.f, 0.f};

  #pragma unroll
  for (int kk = 0; kk < 8; kk++) {
    const u16* Ab = As + (kk < 4 ? 0 : 64 * AS_STRIDE);
    const int kl = (kk & 3) * 32 + quad * 8;
    bf16x8 af[4];
    #pragma unroll
    for (int rt = 0; rt < 4; rt++)
      af[rt] = *(const bf16x8*)(Ab + (rt * 16 + l16) * AS_STRIDE + kl);
    const int kg = kk * 32 + quad * 8;
    #pragma unroll
    for (int ct = 0; ct < 2; ct++) {
      bf16x8 bfv = *(const bf16x8*)(W1T + (size_t)(c0w + ct * 16 + l16) * 256 + kg);
      #pragma unroll
      for (int rt = 0; rt < 4; rt++)
        acc[rt][ct] = __builtin_amdgcn_mfma_f32_16x16x32_bf16(af[rt], bfv, acc[rt][ct], 0, 0, 0);
    }
  }

  float b1v[2];
  #pragma unroll
  for (int ct = 0; ct < 2; ct++) b1v[ct] = b1[c0w + ct * 16 + l16];
  __syncthreads();

  #pragma unroll
  for (int rt = 0; rt < 4; rt++)
    #pragma unroll
    for (int ct = 0; ct < 2; ct++) {
      int n = c0w + ct * 16 + l16;
      #pragma unroll
      for (int r = 0; r < 4; r++)
        t_su[(rt * 16 + quad * 4 + r) * AS_STRIDE + n] = f2bf1(acc[rt][ct][r] + b1v[ct]);
    }
  __syncthreads();

  { // inner LN + SiLU: read t_su, write u_su
    int row = tid >> 2, sub = tid & 3;
    float s = 0.f, sq = 0.f, vals[32];
    #pragma unroll
    for (int i = 0; i < 32; i++) {
      float v = bf2f(t_su[row * AS_STRIDE + sub + i * 4]);
      vals[i] = v; s += v; sq += v * v;
    }
    s += __shfl_xor(s, 1); sq += __shfl_xor(sq, 1);
    s += __shfl_xor(s, 2); sq += __shfl_xor(sq, 2);
    float mean = s * (1.f / 128.f);
    float rstd = rsq_f(sq * (1.f / 128.f) - mean * mean + 1e-5f);
    #pragma unroll
    for (int i = 0; i < 32; i++) {
      int c = sub + i * 4;
      float a = (vals[i] - mean) * rstd * g[c] + be[c];
      u_su[row * AS_STRIDE + c] = f2bf1(silu_f(a));
    }
  }
  __syncthreads();

  f32x4 acc2[4][2];
  #pragma unroll
  for (int rt = 0; rt < 4; rt++)
    #pragma unroll
    for (int ct = 0; ct < 2; ct++)
      acc2[rt][ct] = (f32x4){0.f, 0.f, 0.f, 0.f};

  #pragma unroll
  for (int kk = 0; kk < 4; kk++) {
    const int kl = kk * 32 + quad * 8;
    bf16x8 af[4];
    #pragma unroll
    for (int rt = 0; rt < 4; rt++)
      af[rt] = *(const bf16x8*)(u_su + (rt * 16 + l16) * AS_STRIDE + kl);
    #pragma unroll
    for (int ct = 0; ct < 2; ct++) {
      bf16x8 bfv = *(const bf16x8*)(W2T + (size_t)(c0w + ct * 16 + l16) * 128 + kl);
      #pragma unroll
      for (int rt = 0; rt < 4; rt++)
        acc2[rt][ct] = __builtin_amdgcn_mfma_f32_16x16x32_bf16(af[rt], bfv, acc2[rt][ct], 0, 0, 0);
    }
  }
  __syncthreads();

  #pragma unroll
  for (int ct = 0; ct < 2; ct++) {
    int n = c0w + ct * 16 + l16;
    float b2v = b2[n];
    #pragma unroll
    for (int rt = 0; rt < 4; rt++)
      #pragma unroll
      for (int r = 0; r < 4; r++) {
        int m = rt * 16 + quad * 4 + r;
        int node = m0 + m; if (node >= Nn) node = Nn - 1;
        t_su[m * AS_STRIDE + n] =
            f2bf1(acc2[rt][ct][r] + b2v + bf2f(hbf[(size_t)node * 128 + n]));
      }
  }
  __syncthreads();

  { // outer LN -> hbf and back into t_su (A-layout h)
    int row = tid >> 2, sub = tid & 3;
    int node = m0 + row;
    float s = 0.f, sq = 0.f, vals[32];
    #pragma unroll
    for (int i = 0; i < 32; i++) {
      float v = bf2f(t_su[row * AS_STRIDE + sub + i * 4]);
      vals[i] = v; s += v; sq += v * v;
    }
    s += __shfl_xor(s, 1); sq += __shfl_xor(sq, 1);
    s += __shfl_xor(s, 2); sq += __shfl_xor(sq, 2);
    float mean = s * (1.f / 128.f);
    float rstd = rsq_f(sq * (1.f / 128.f) - mean * mean + 1e-5f);
    #pragma unroll
    for (int i = 0; i < 32; i++) {
      int c = sub + i * 4;
      float v = (vals[i] - mean) * rstd * lng[c] + lnb[c];
      u16 hb = f2bf1(v);
      t_su[row * AS_STRIDE + c] = hb;
      if (node < Nn) hbf[(size_t)node * 128 + c] = hb;
    }
  }

  if (W1Tn != nullptr) { // fused next-layer hd = h@W1d + b1, hs = h@W1s
    __syncthreads();
    f32x4 ah[4][2];
    #pragma unroll
    for (int rt = 0; rt < 4; rt++)
      #pragma unroll
      for (int ct = 0; ct < 2; ct++)
        ah[rt][ct] = (f32x4){0.f, 0.f, 0.f, 0.f};
    #pragma unroll
    for (int kk = 0; kk < 4; kk++) {
      const int kl = kk * 32 + quad * 8;
      bf16x8 af[4];
      #pragma unroll
      for (int rt = 0; rt < 4; rt++)
        af[rt] = *(const bf16x8*)(t_su + (rt * 16 + l16) * AS_STRIDE + kl);
      #pragma unroll
      for (int ct = 0; ct < 2; ct++) {
        bf16x8 bd = *(const bf16x8*)(W1Tn + (size_t)(c0w + ct * 16 + l16) * 256 + kl);
        #pragma unroll
        for (int rt = 0; rt < 4; rt++)
          ah[rt][ct] = __builtin_amdgcn_mfma_f32_16x16x32_bf16(af[rt], bd, ah[rt][ct], 0, 0, 0);
      }
    }
    #pragma unroll
    for (int ct = 0; ct < 2; ct++) {
      int n = c0w + ct * 16 + l16;
      float bv = b1n[n];
      #pragma unroll
      for (int rt = 0; rt < 4; rt++)
        #pragma unroll
        for (int r = 0; r < 4; r++) {
          int node = m0 + rt * 16 + quad * 4 + r;
          if (node < Nn) hd_all[(size_t)node * 128 + n] = f2bf1(ah[rt][ct][r] + bv);
        }
    }
    #pragma unroll
    for (int rt = 0; rt < 4; rt++)
      #pragma unroll
      for (int ct = 0; ct < 2; ct++)
        ah[rt][ct] = (f32x4){0.f, 0.f, 0.f, 0.f};
    #pragma unroll
    for (int kk = 0; kk < 4; kk++) {
      const int kl = kk * 32 + quad * 8;
      bf16x8 af[4];
      #pragma unroll
      for (int rt = 0; rt < 4; rt++)
        af[rt] = *(const bf16x8*)(t_su + (rt * 16 + l16) * AS_STRIDE + kl);
      #pragma unroll
      for (int ct = 0; ct < 2; ct++) {
        bf16x8 bs = *(const bf16x8*)(W1Tn + (size_t)(c0w + ct * 16 + l16) * 256 + 128 + kl);
        #pragma unroll
        for (int rt = 0; rt < 4; rt++)
          ah[rt][ct] = __builtin_amdgcn_mfma_f32_16x16x32_bf16(af[rt], bs, ah[rt][ct], 0, 0, 0);
      }
    }
    #pragma unroll
    for (int ct = 0; ct < 2; ct++) {
      int n = c0w + ct * 16 + l16;
      #pragma unroll
      for (int rt = 0; rt < 4; rt++)
        #pragma unroll
        for (int r = 0; r < 4; r++) {
          int node = m0 + rt * 16 + quad * 4 + r;
          if (node < Nn) hs_all[(size_t)node * 128 + n] = f2bf1(ah[rt][ct][r]);
        }
    }
  }

  if (dW1T != nullptr) { // fused decoder (layer 2): h in t_su (A-layout)
    __syncthreads();
    f32x4 da[4][2];
    #pragma unroll
    for (int rt = 0; rt < 4; rt++)
      #pragma unroll
      for (int ct = 0; ct < 2; ct++)
        da[rt][ct] = (f32x4){0.f, 0.f, 0.f, 0.f};
    #pragma unroll
    for (int kk = 0; kk < 4; kk++) {
      const int kl = kk * 32 + quad * 8;
      bf16x8 af[4];
      #pragma unroll
      for (int rt = 0; rt < 4; rt++)
        af[rt] = *(const bf16x8*)(t_su + (rt * 16 + l16) * AS_STRIDE + kl);
      #pragma unroll
      for (int ct = 0; ct < 2; ct++) {
        bf16x8 bfv = *(const bf16x8*)(dW1T + (size_t)(c0w + ct * 16 + l16) * 128 + kl);
        #pragma unroll
        for (int rt = 0; rt < 4; rt++)
          da[rt][ct] = __builtin_amdgcn_mfma_f32_16x16x32_bf16(af[rt], bfv, da[rt][ct], 0, 0, 0);
      }
    }
    __syncthreads();
    #pragma unroll
    for (int ct = 0; ct < 2; ct++) {
      int n = c0w + ct * 16 + l16;
      float bv = db1[n];
      #pragma unroll
      for (int rt = 0; rt < 4; rt++)
        #pragma unroll
        for (int r = 0; r < 4; r++)
          u_su[(rt * 16 + quad * 4 + r) * AS_STRIDE + n] = f2bf1(silu_f(da[rt][ct][r] + bv));
    }
    __syncthreads();
    { // dec L2: 64 cols, wave covers 16; u2 overwrites t_su region
      const int c0b = w * 16;
      f32x4 a2[4];
      #pragma unroll
      for (int rt = 0; rt < 4; rt++) a2[rt] = (f32x4){0.f, 0.f, 0.f, 0.f};
      #pragma unroll
      for (int kk = 0; kk < 4; kk++) {
        const int kl = kk * 32 + quad * 8;
        bf16x8 af[4];
        #pragma unroll
        for (int rt = 0; rt < 4; rt++)
          af[rt] = *(const bf16x8*)(u_su + (rt * 16 + l16) * AS_STRIDE + kl);
        bf16x8 bfv = *(const bf16x8*)(dW2T + (size_t)(c0b + l16) * 128 + kl);
        #pragma unroll
        for (int rt = 0; rt < 4; rt++)
          a2[rt] = __builtin_amdgcn_mfma_f32_16x16x32_bf16(af[rt], bfv, a2[rt], 0, 0, 0);
      }
      float bv = db2[c0b + l16];
      #pragma unroll
      for (int rt = 0; rt < 4; rt++)
        #pragma unroll
        for (int r = 0; r < 4; r++)
          t_su[(rt * 16 + quad * 4 + r) * 72 + c0b + l16] = f2bf1(silu_f(a2[rt][r] + bv));
    }
    __syncthreads();
    if (w == 0) { // dec L3: 6 cols (padded 16), K=64
      f32x4 a3[4];
      #pragma unroll
      for (int rt = 0; rt < 4; rt++) a3[rt] = (f32x4){0.f, 0.f, 0.f, 0.f};
      #pragma unroll
      for (int kk = 0; kk < 2; kk++) {
        const int kl = kk * 32 + quad * 8;
        bf16x8 af[4];
        #pragma unroll
        for (int rt = 0; rt < 4; rt++)
          af[rt] = *(const bf16x8*)(t_su + (rt * 16 + l16) * 72 + kl);
        bf16x8 bfv = *(const bf16x8*)(dW3T + l16 * 64 + kl);
        #pragma unroll
        for (int rt = 0; rt < 4; rt++)
          a3[rt] = __builtin_amdgcn_mfma_f32_16x16x32_bf16(af[rt], bfv, a3[rt], 0, 0, 0);
      }
      if (l16 < 6) {
        float bv = db3[l16];
        #pragma unroll
        for (int rt = 0; rt < 4; rt++)
          #pragma unroll
          for (int r = 0; r < 4; r++) {
            int node = m0 + rt * 16 + quad * 4 + r;
            if (node < Nn)
              out[(size_t)node * 6 + l16] = a3[rt][r] + bv + x[node * 7 + l16];
          }
      }
    }
  }
}

// ---------------- host launcher ----------------------------------------------
extern "C" void kernel_launch(void* const* d_in, const int* in_sizes, int n_in,
                              void* d_out, int out_size, void* d_ws, size_t ws_size,
                              hipStream_t stream) {
  const float* x      = (const float*)d_in[0];
  const float* pos    = (const float*)d_in[1];
  const int*   eidx   = (const int*)d_in[2];
  const float* enc_w1 = (const float*)d_in[3];
  const float* enc_b1 = (const float*)d_in[4];
  const float* enc_g  = (const float*)d_in[5];
  const float* enc_be = (const float*)d_in[6];
  const float* enc_w2 = (const float*)d_in[7];
  const float* enc_b2 = (const float*)d_in[8];
  const float* e_w1   = (const float*)d_in[9];
  const float* e_b1   = (const float*)d_in[10];
  const float* e_g    = (const float*)d_in[11];
  const float* e_be   = (const float*)d_in[12];
  const float* e_w2   = (const float*)d_in[13];
  const float* e_b2   = (const float*)d_in[14];
  const float* n_w1   = (const float*)d_in[15];
  const float* n_b1   = (const float*)d_in[16];
  const float* n_g    = (const float*)d_in[17];
  const float* n_be   = (const float*)d_in[18];
  const float* n_w2   = (const float*)d_in[19];
  const float* n_b2   = (const float*)d_in[20];
  const float* ln_g   = (const float*)d_in[21];
  const float* ln_b   = (const float*)d_in[22];
  const float* dec_w1 = (const float*)d_in[23];
  const float* dec_b1 = (const float*)d_in[24];
  const float* dec_w2 = (const float*)d_in[25];
  const float* dec_b2 = (const float*)d_in[26];
  const float* dec_w3 = (const float*)d_in[27];
  const float* dec_b3 = (const float*)d_in[28];

  const int N = in_sizes[0] / 7;          // 50000
  const int E = in_sizes[2] / 2;          // 1600000

  char* ws = (char*)d_ws;
  size_t off = 0;
  u16*   hbf    = (u16*)(ws + off);   off += (size_t)N * 128 * 2;
  u16*   hd_all = (u16*)(ws + off);   off += (size_t)N * 128 * 2;
  u16*   hs_all = (u16*)(ws + off);   off += (size_t)N * 128 * 2;
  float* aggr   = (float*)(ws + off); off += (size_t)N * 128 * 4;
  u16* eW1T = (u16*)(ws + off); off += 3 * 128 * 256 * 2;
  u16* eW2T = (u16*)(ws + off); off += 3 * 128 * 128 * 2;
  u16* nW1T = (u16*)(ws + off); off += 3 * 128 * 256 * 2;
  u16* nW2T = (u16*)(ws + off); off += 3 * 128 * 128 * 2;
  u16* encW1T = (u16*)(ws + off); off += 128 * 32 * 2;
  u16* encW2T = (u16*)(ws + off); off += 128 * 128 * 2;
  u16* decW1T = (u16*)(ws + off); off += 128 * 128 * 2;
  u16* decW2T = (u16*)(ws + off); off += 64 * 128 * 2;
  u16* decW3T = (u16*)(ws + off); off += 16 * 64 * 2;
  int* cnt    = (int*)(ws + off); off += (size_t)N * 4;
  int* cursor = (int*)(ws + off); off += (size_t)N * 4;
  int2* sedge = (int2*)(ws + off); off += (size_t)E * 8;

  // sort edges by dst once (reused across all 3 layers); cnt preserved for node
  hipMemsetAsync(cnt, 0, (size_t)N * 4, stream);
  edge_hist<<<(E + 255) / 256, 256, 0, stream>>>(eidx + E, E, cnt);
  scan_kernel<<<1, 1024, 0, stream>>>(cnt, cursor, N);
  edge_scatter<<<(E + 255) / 256, 256, 0, stream>>>(eidx, eidx + E, E, cursor, sedge);

  prep_weights<<<1152, 256, 0, stream>>>(e_w1, e_w2, n_w1, n_w2, eW1T, eW2T, nW1T, nW2T);
  prep_weights2<<<180, 256, 0, stream>>>(enc_w1, enc_w2, dec_w1, dec_w2, dec_w3,
                                         encW1T, encW2T, decW1T, decW2T, decW3T);

  // zero aggr ONCE; node_mlp re-zeroes its rows for the next layer after reading
  hipMemsetAsync(aggr, 0, (size_t)N * 128 * 4, stream);

  const int nblk = (N + 63) / 64;
  encoder_mfma<<<nblk, 256, 0, stream>>>(x, encW1T, enc_b1, enc_g, enc_be, encW2T, enc_b2,
                                         eW1T, e_b1, hbf, hd_all, hs_all, N);

  for (int l = 0; l < 3; l++) {
    edge_mlp_kernel<<<E / 64, 256, 0, stream>>>(
        sedge, pos, hd_all, hs_all,
        e_w1 + (size_t)l * 33408 + 256 * 128,   // W1c rows as f32 [5][128]
        e_g + l * 128, e_be + l * 128,
        eW2T + (size_t)l * 128 * 128, aggr);
    const u16* W1Tn = (l < 2) ? (eW1T + (size_t)(l + 1) * 128 * 256) : (const u16*)nullptr;
    const bool last = (l == 2);
    node_mlp_kernel<<<nblk, 256, 0, stream>>>(
        hbf, aggr, cnt, e_b2 + l * 128,
        nW1T + (size_t)l * 128 * 256, n_b1 + l * 128, n_g + l * 128, n_be + l * 128,
        nW2T + (size_t)l * 128 * 128, n_b2 + l * 128,
        ln_g + l * 128, ln_b + l * 128,
        W1Tn, e_b1 + ((l + 1) % 3) * 128, hd_all, hs_all,
        x,
        last ? decW1T : (const u16*)nullptr, dec_b1,
        last ? decW2T : (const u16*)nullptr, dec_b2,
        last ? decW3T : (const u16*)nullptr, dec_b3,
        (float*)d_out, N);
  }
}